// Round 1
// baseline (612.555 us; speedup 1.0000x reference)
//
#include <hip/hip_runtime.h>
#include <math.h>

#define N_NODES 50000
#define E_EDGES 250000
#define HD 256          // H * D per edge type
#define NH 4
#define DH 64
#define NC 153
#define KDIM 256        // all GEMMs have K = 256
#define HD2 512         // both edge types concatenated

// ---------- fp32 <-> bf16 ----------
__device__ __forceinline__ unsigned short f2bf(float f) {
    unsigned u = __float_as_uint(f);
    u = u + 0x7FFFu + ((u >> 16) & 1u);
    return (unsigned short)(u >> 16);
}
__device__ __forceinline__ float bf2f(unsigned short b) {
    return __uint_as_float(((unsigned)b) << 16);
}

typedef __attribute__((ext_vector_type(8))) short bf16x8;
typedef __attribute__((ext_vector_type(4))) float f32x4;

// ============ output-stationary K=256 GEMM: 64 rows x (NT*64) cols/block ============
// C[M,Ncols] = A[M,256] @ BT[Ncols,256]^T (+bias). BT zero-padded to >= NT*64 rows.
// 4 waves per block; wave w computes rows[row0..row0+63] x cols[w*NT*16 .. +NT*16).
// A tile (64x256 bf16 = 32KB) staged ONCE into XOR-swizzled LDS, shared by all waves.
// B (<=256KB total) is L2-resident on every XCD -> streamed from global, reg-dbuf.
// Exactly ONE __syncthreads per block; no per-K-step barriers.
template<int NT>
__global__ __launch_bounds__(256) void gemm_a_lds(
        const unsigned short* __restrict__ A, const unsigned short* __restrict__ BT,
        float* __restrict__ Cf, unsigned short* __restrict__ Cbf,
        const float* __restrict__ bias, int M, int Ncols) {
    __shared__ unsigned short As[64 * 256];   // 32 KB, rows XOR-swizzled
    const int tid  = threadIdx.x;
    const int lane = tid & 63;
    const int wave = tid >> 6;
    const int l16  = lane & 15;
    const int quad = lane >> 4;
    const int row0 = blockIdx.x * 64;
    const int wcol = wave * (NT * 16);

    // ---- stage A(row0..row0+63, 0..255) -> LDS, swizzle byte ^= (row&7)<<4 ----
    // (row stride 512B would otherwise be a 16-way bank conflict on ds_read_b128)
    #pragma unroll
    for (int j = 0; j < 8; j++) {
        const int c  = tid + 256 * j;        // 16B chunk id (2048 total)
        const int r  = c >> 5;               // row within tile (32 chunks/row)
        const int kb = (c & 31) << 4;        // byte offset within row
        int grow = row0 + r; if (grow >= M) grow = M - 1;   // clamp tail reads
        const uint4 v = *(const uint4*)((const char*)A + (size_t)grow * 512 + kb);
        *(uint4*)((char*)As + r * 512 + (kb ^ ((r & 7) << 4))) = v;
    }
    __syncthreads();

    f32x4 acc[4][NT];
    #pragma unroll
    for (int i = 0; i < 4; i++)
        #pragma unroll
        for (int n = 0; n < NT; n++) acc[i][n] = (f32x4)0.f;

    // per-lane B base: row (=C col) wcol+l16, k offset quad*8
    const unsigned short* bptr = BT + (size_t)(wcol + l16) * KDIM + quad * 8;

    bf16x8 a_cur[4], b_cur[NT], a_nxt[4], b_nxt[NT];
    #pragma unroll
    for (int mt = 0; mt < 4; mt++) {
        const int r = mt * 16 + l16;
        a_cur[mt] = *(const bf16x8*)((const char*)As + r * 512 +
                        ((quad * 16) ^ ((r & 7) << 4)));
    }
    #pragma unroll
    for (int n = 0; n < NT; n++)
        b_cur[n] = *(const bf16x8*)(bptr + (size_t)n * 16 * KDIM);

    #pragma unroll
    for (int kk = 0; kk < 8; kk++) {
        if (kk < 7) {
            const int kb1 = (kk + 1) * 64;          // byte offset of next K-step
            #pragma unroll
            for (int mt = 0; mt < 4; mt++) {
                const int r = mt * 16 + l16;
                a_nxt[mt] = *(const bf16x8*)((const char*)As + r * 512 +
                                ((kb1 + quad * 16) ^ ((r & 7) << 4)));
            }
            #pragma unroll
            for (int n = 0; n < NT; n++)
                b_nxt[n] = *(const bf16x8*)(bptr + (size_t)n * 16 * KDIM +
                                            (kk + 1) * 32);
        }
        #pragma unroll
        for (int mt = 0; mt < 4; mt++)
            #pragma unroll
            for (int nt = 0; nt < NT; nt++)
                acc[mt][nt] = __builtin_amdgcn_mfma_f32_16x16x32_bf16(
                                  a_cur[mt], b_cur[nt], acc[mt][nt], 0, 0, 0);
        #pragma unroll
        for (int t = 0; t < 4; t++) a_cur[t] = a_nxt[t];
        #pragma unroll
        for (int n = 0; n < NT; n++) b_cur[n] = b_nxt[n];
    }

    #pragma unroll
    for (int mt = 0; mt < 4; mt++) {
        #pragma unroll
        for (int nt = 0; nt < NT; nt++) {
            const int n = wcol + nt * 16 + l16;
            if (n >= Ncols) continue;
            const float bv = bias ? bias[n] : 0.f;
            #pragma unroll
            for (int r = 0; r < 4; r++) {
                const int m = row0 + mt * 16 + quad * 4 + r;
                if (m < M) {
                    const float v = acc[mt][nt][r] + bv;
                    if (Cf)  Cf[(size_t)m * Ncols + n] = v;
                    if (Cbf) Cbf[(size_t)m * Ncols + n] = f2bf(v);
                }
            }
        }
    }
}

// ---------- fp32 -> bf16 conversion (vectorized) ----------
__global__ __launch_bounds__(256) void convert_bf16_kernel(
        const float* __restrict__ in, unsigned short* __restrict__ out, int n) {
    const int i = (blockIdx.x * 256 + threadIdx.x) * 4;
    if (i + 3 < n) {
        const float4 v = *(const float4*)&in[i];
        ushort4 o;
        o.x = f2bf(v.x); o.y = f2bf(v.y); o.z = f2bf(v.z); o.w = f2bf(v.w);
        *(ushort4*)&out[i] = o;
    } else {
        for (int j = i; j < n; j++) out[j] = f2bf(in[j]);
    }
}

// ---------- dual weight transpose+convert: Wa,Wb[K,256] -> Wt[512,K] bf16 ----------
__global__ __launch_bounds__(256) void wt2_kernel(
        const float* __restrict__ Wa, const float* __restrict__ Wb,
        unsigned short* __restrict__ Wt) {
    const int idx = blockIdx.x * 256 + threadIdx.x;
    const int n = idx >> 8, k = idx & 255;
    Wt[idx] = (n < HD) ? f2bf(Wa[(size_t)k * HD + n])
                       : f2bf(Wb[(size_t)k * HD + (n - HD)]);
}

// ---------- single weight transpose+convert with zero-pad to 256 rows ----------
__global__ __launch_bounds__(256) void wt_kernel(
        const float* __restrict__ W, unsigned short* __restrict__ Wt, int Nc) {
    const int idx = blockIdx.x * 256 + threadIdx.x;
    const int n = idx >> 8, k = idx & 255;
    Wt[idx] = (n < Nc) ? f2bf(W[(size_t)k * Nc + n]) : (unsigned short)0;
}

// ---------- CSR construction ----------
__global__ __launch_bounds__(256) void zero_int_kernel(int* __restrict__ p, int n) {
    const int i = blockIdx.x * 256 + threadIdx.x;
    if (i < n) p[i] = 0;
}

__global__ __launch_bounds__(256) void hist_kernel(
        const int* __restrict__ ei, int* __restrict__ deg) {
    const int e = blockIdx.x * 256 + threadIdx.x;
    if (e < E_EDGES) atomicAdd(&deg[ei[E_EDGES + e]], 1);
}

__global__ __launch_bounds__(1024) void scan_local_kernel(
        const int* __restrict__ deg, int* __restrict__ excl,
        int* __restrict__ bsums, int n) {
    __shared__ int wsum[16];
    const int i = blockIdx.x * 1024 + threadIdx.x;
    const int lane = threadIdx.x & 63;
    const int wid = threadIdx.x >> 6;
    const int v = (i < n) ? deg[i] : 0;
    int s = v;
    #pragma unroll
    for (int off = 1; off < 64; off <<= 1) {
        const int t = __shfl_up(s, off);
        if (lane >= off) s += t;
    }
    if (lane == 63) wsum[wid] = s;
    __syncthreads();
    if (wid == 0) {
        int wv = (lane < 16) ? wsum[lane] : 0;
        #pragma unroll
        for (int off = 1; off < 16; off <<= 1) {
            const int t = __shfl_up(wv, off);
            if (lane >= off) wv += t;
        }
        if (lane < 16) wsum[lane] = wv;
    }
    __syncthreads();
    const int woff = (wid > 0) ? wsum[wid - 1] : 0;
    if (i < n) excl[i] = s - v + woff;
    if (threadIdx.x == 1023) bsums[blockIdx.x] = wsum[15];
}

__global__ __launch_bounds__(64) void scan_bsums_kernel(
        int* __restrict__ bsums, int* __restrict__ row_ptr, int nb, int n) {
    const int lane = threadIdx.x;
    const int v = (lane < nb) ? bsums[lane] : 0;
    int s = v;
    #pragma unroll
    for (int off = 1; off < 64; off <<= 1) {
        const int t = __shfl_up(s, off);
        if (lane >= off) s += t;
    }
    if (lane < nb) bsums[lane] = s - v;
    if (lane == 63) row_ptr[n] = s;
}

__global__ __launch_bounds__(256) void scan_add_kernel(
        const int* __restrict__ excl, const int* __restrict__ bsums,
        int* __restrict__ row_ptr, int* __restrict__ cursor, int n) {
    const int i = blockIdx.x * 256 + threadIdx.x;
    if (i >= n) return;
    const int v = excl[i] + bsums[i >> 10];
    row_ptr[i] = v;
    cursor[i]  = v;
}

__global__ __launch_bounds__(256) void scatter_kernel(
        const int* __restrict__ ei, int* __restrict__ cursor,
        int* __restrict__ col_src, int* __restrict__ col_dst) {
    const int e = blockIdx.x * 256 + threadIdx.x;
    if (e >= E_EDGES) return;
    const int src = ei[e], dst = ei[E_EDGES + e];
    const int pos = atomicAdd(&cursor[dst], 1);
    col_src[pos] = src;
    col_dst[pos] = dst;
}

// ---------- per-node attention scores for BOTH etypes ----------
__global__ __launch_bounds__(256) void scores2_kernel(
        const unsigned short* __restrict__ h_ab,
        const float* __restrict__ as_a, const float* __restrict__ ad_a,
        const float* __restrict__ as_b, const float* __restrict__ ad_b,
        float* __restrict__ ssrc8, float* __restrict__ sdst8) {
    const int node = blockIdx.x * 4 + (threadIdx.x >> 6);
    const int lane = threadIdx.x & 63;
    if (node >= N_NODES) return;
    const size_t base = (size_t)node * HD2 + lane * 4;

    const ushort4 ha = *(const ushort4*)&h_ab[base];
    const ushort4 hb = *(const ushort4*)&h_ab[base + HD];
    const float4 asa = *(const float4*)&as_a[lane * 4];
    const float4 ada = *(const float4*)&ad_a[lane * 4];
    const float4 asb = *(const float4*)&as_b[lane * 4];
    const float4 adb = *(const float4*)&ad_b[lane * 4];
    const float a0 = bf2f(ha.x), a1 = bf2f(ha.y), a2 = bf2f(ha.z), a3 = bf2f(ha.w);
    const float b0 = bf2f(hb.x), b1 = bf2f(hb.y), b2 = bf2f(hb.z), b3 = bf2f(hb.w);

    float rsa = a0 * asa.x + a1 * asa.y + a2 * asa.z + a3 * asa.w;
    float rda = a0 * ada.x + a1 * ada.y + a2 * ada.z + a3 * ada.w;
    float rsb = b0 * asb.x + b1 * asb.y + b2 * asb.z + b3 * asb.w;
    float rdb = b0 * adb.x + b1 * adb.y + b2 * adb.z + b3 * adb.w;
    #pragma unroll
    for (int off = 1; off < 16; off <<= 1) {
        rsa += __shfl_xor(rsa, off);
        rda += __shfl_xor(rda, off);
        rsb += __shfl_xor(rsb, off);
        rdb += __shfl_xor(rdb, off);
    }
    if ((lane & 15) == 0) {
        const int hh = lane >> 4;
        ssrc8[node * 8 + 0 + hh] = rsa;
        sdst8[node * 8 + 0 + hh] = rda;
        ssrc8[node * 8 + 4 + hh] = rsb;
        sdst8[node * 8 + 4 + hh] = rdb;
    }
}

// ---------- S1: per (node,etype,head) thread computes m and 1/(z+eps) ----------
__global__ __launch_bounds__(256) void seg_mz8_kernel(
        const int* __restrict__ rp_a, const int* __restrict__ cs_a,
        const int* __restrict__ rp_b, const int* __restrict__ cs_b,
        const float* __restrict__ ssrc8, const float* __restrict__ sdst8,
        float* __restrict__ m8, float* __restrict__ zr8) {
    const int t = blockIdx.x * 256 + threadIdx.x;
    if (t >= N_NODES * 8) return;
    const int node = t >> 3;
    const int r8 = t & 7;
    const int et = r8 >> 2;
    const int* rp = et ? rp_b : rp_a;
    const int* cs = et ? cs_b : cs_a;
    const int beg = rp[node], end = rp[node + 1];
    const float sd = sdst8[t];
    float m = -INFINITY;
    for (int e = beg; e < end; e++) {
        float s = ssrc8[cs[e] * 8 + r8] + sd;
        s = (s >= 0.f) ? s : 0.2f * s;
        m = fmaxf(m, s);
    }
    float z = 0.f;
    for (int e = beg; e < end; e++) {
        float s = ssrc8[cs[e] * 8 + r8] + sd;
        s = (s >= 0.f) ? s : 0.2f * s;
        z += expf(s - m);
    }
    m8[t]  = m;
    zr8[t] = 1.f / (z + 1e-16f);
}

// ---------- S2: per (edge,head) alpha in CSR order, one etype ----------
__global__ __launch_bounds__(256) void alpha_kernel(
        const int* __restrict__ cs, const int* __restrict__ cd,
        const float* __restrict__ ssrc8, const float* __restrict__ sdst8,
        const float* __restrict__ m8, const float* __restrict__ zr8,
        float* __restrict__ ebuf, int et) {
    const int t = blockIdx.x * 256 + threadIdx.x;
    if (t >= E_EDGES * NH) return;
    const int pos = t >> 2, hh = t & 3;
    const int r8 = et * 4 + hh;
    const int src = cs[pos], dst = cd[pos];
    float s = ssrc8[src * 8 + r8] + sdst8[dst * 8 + r8];
    s = (s >= 0.f) ? s : 0.2f * s;
    ebuf[t] = expf(s - m8[dst * 8 + r8]) * zr8[dst * 8 + r8];
}

// ---------- S3: aggregation + fused epilogue (bias, leaky, bf16 write) ----------
__global__ __launch_bounds__(256) void aggregate_both_kernel(
        const int* __restrict__ rp_a, const int* __restrict__ cs_a,
        const int* __restrict__ rp_b, const int* __restrict__ cs_b,
        const unsigned short* __restrict__ h_ab,
        const float* __restrict__ ebuf_a, const float* __restrict__ ebuf_b,
        const float* __restrict__ b1, const float* __restrict__ b2,
        unsigned short* __restrict__ out_bf, int do_leaky) {
    const int node = blockIdx.x * 4 + (threadIdx.x >> 6);
    const int lane = threadIdx.x & 63;
    if (node >= N_NODES) return;
    const int hh = lane >> 4;
    const int c4 = lane * 4;

    float4 a = make_float4(0.f, 0.f, 0.f, 0.f);

    #pragma unroll
    for (int et = 0; et < 2; et++) {
        const int* rp = et ? rp_b : rp_a;
        const int* cs = et ? cs_b : cs_a;
        const float* eb = et ? ebuf_b : ebuf_a;
        const size_t hoff = et ? (size_t)HD : 0;
        const int beg = rp[node], end = rp[node + 1];
        int e = beg;
        for (; e + 3 < end; e += 4) {
            const int s0 = cs[e + 0], s1 = cs[e + 1],
                      s2 = cs[e + 2], s3 = cs[e + 3];
            const float al0 = eb[(e + 0) * NH + hh];
            const float al1 = eb[(e + 1) * NH + hh];
            const float al2 = eb[(e + 2) * NH + hh];
            const float al3 = eb[(e + 3) * NH + hh];
            const ushort4 h0 = *(const ushort4*)&h_ab[(size_t)s0 * HD2 + hoff + c4];
            const ushort4 h1 = *(const ushort4*)&h_ab[(size_t)s1 * HD2 + hoff + c4];
            const ushort4 h2 = *(const ushort4*)&h_ab[(size_t)s2 * HD2 + hoff + c4];
            const ushort4 h3 = *(const ushort4*)&h_ab[(size_t)s3 * HD2 + hoff + c4];
            a.x = fmaf(al0, bf2f(h0.x), a.x); a.y = fmaf(al0, bf2f(h0.y), a.y);
            a.z = fmaf(al0, bf2f(h0.z), a.z); a.w = fmaf(al0, bf2f(h0.w), a.w);
            a.x = fmaf(al1, bf2f(h1.x), a.x); a.y = fmaf(al1, bf2f(h1.y), a.y);
            a.z = fmaf(al1, bf2f(h1.z), a.z); a.w = fmaf(al1, bf2f(h1.w), a.w);
            a.x = fmaf(al2, bf2f(h2.x), a.x); a.y = fmaf(al2, bf2f(h2.y), a.y);
            a.z = fmaf(al2, bf2f(h2.z), a.z); a.w = fmaf(al2, bf2f(h2.w), a.w);
            a.x = fmaf(al3, bf2f(h3.x), a.x); a.y = fmaf(al3, bf2f(h3.y), a.y);
            a.z = fmaf(al3, bf2f(h3.z), a.z); a.w = fmaf(al3, bf2f(h3.w), a.w);
        }
        for (; e < end; e++) {
            const int src = cs[e];
            const float al = eb[e * NH + hh];
            const ushort4 hv = *(const ushort4*)&h_ab[(size_t)src * HD2 + hoff + c4];
            a.x = fmaf(al, bf2f(hv.x), a.x);
            a.y = fmaf(al, bf2f(hv.y), a.y);
            a.z = fmaf(al, bf2f(hv.z), a.z);
            a.w = fmaf(al, bf2f(hv.w), a.w);
        }
    }

    const float4 bv1 = *(const float4*)&b1[c4];
    const float4 bv2 = *(const float4*)&b2[c4];
    float4 v;
    v.x = a.x + bv1.x + bv2.x;
    v.y = a.y + bv1.y + bv2.y;
    v.z = a.z + bv1.z + bv2.z;
    v.w = a.w + bv1.w + bv2.w;
    if (do_leaky) {
        v.x = (v.x >= 0.f) ? v.x : 0.01f * v.x;
        v.y = (v.y >= 0.f) ? v.y : 0.01f * v.y;
        v.z = (v.z >= 0.f) ? v.z : 0.01f * v.z;
        v.w = (v.w >= 0.f) ? v.w : 0.01f * v.w;
    }
    ushort4 o;
    o.x = f2bf(v.x); o.y = f2bf(v.y); o.z = f2bf(v.z); o.w = f2bf(v.w);
    *(ushort4*)&out_bf[(size_t)node * HD + c4] = o;
}

// ---------- host-side helpers ----------
static void run_layer(const unsigned short* a_bf,
                      const int* rp_a, const int* cs_a, const int* cd_a,
                      const int* rp_b, const int* cs_b, const int* cd_b,
                      const float* Wa, const float* Wb,
                      const float* as_a, const float* ad_a,
                      const float* as_b, const float* ad_b,
                      const float* b1, const float* b2,
                      unsigned short* Wt2, unsigned short* h_ab,
                      float* ssrc8, float* sdst8, float* m8, float* zr8,
                      float* ebuf_a, float* ebuf_b,
                      unsigned short* out_bf, int do_leaky,
                      hipStream_t stream) {
    wt2_kernel<<<HD2, 256, 0, stream>>>(Wa, Wb, Wt2);
    gemm_a_lds<8><<<(N_NODES + 63) / 64, 256, 0, stream>>>(
        a_bf, Wt2, nullptr, h_ab, nullptr, N_NODES, HD2);
    scores2_kernel<<<(N_NODES + 3) / 4, 256, 0, stream>>>(
        h_ab, as_a, ad_a, as_b, ad_b, ssrc8, sdst8);
    seg_mz8_kernel<<<(N_NODES * 8 + 255) / 256, 256, 0, stream>>>(
        rp_a, cs_a, rp_b, cs_b, ssrc8, sdst8, m8, zr8);
    const int ab = (E_EDGES * NH + 255) / 256;
    alpha_kernel<<<ab, 256, 0, stream>>>(cs_a, cd_a, ssrc8, sdst8, m8, zr8, ebuf_a, 0);
    alpha_kernel<<<ab, 256, 0, stream>>>(cs_b, cd_b, ssrc8, sdst8, m8, zr8, ebuf_b, 1);
    aggregate_both_kernel<<<(N_NODES + 3) / 4, 256, 0, stream>>>(
        rp_a, cs_a, rp_b, cs_b, h_ab, ebuf_a, ebuf_b, b1, b2, out_bf, do_leaky);
}

static void build_csr(const int* ei, int* deg, int* cursor, int* row_ptr,
                      int* col_src, int* col_dst, int* excl, int* bsums,
                      hipStream_t stream) {
    const int nb  = (N_NODES + 255) / 256;
    const int eb  = (E_EDGES + 255) / 256;
    const int sb  = (N_NODES + 1023) / 1024;
    zero_int_kernel<<<nb, 256, 0, stream>>>(deg, N_NODES);
    hist_kernel<<<eb, 256, 0, stream>>>(ei, deg);
    scan_local_kernel<<<sb, 1024, 0, stream>>>(deg, excl, bsums, N_NODES);
    scan_bsums_kernel<<<1, 64, 0, stream>>>(bsums, row_ptr, sb, N_NODES);
    scan_add_kernel<<<nb, 256, 0, stream>>>(excl, bsums, row_ptr, cursor, N_NODES);
    scatter_kernel<<<eb, 256, 0, stream>>>(ei, cursor, col_src, col_dst);
}

extern "C" void kernel_launch(void* const* d_in, const int* in_sizes, int n_in,
                              void* d_out, int out_size, void* d_ws, size_t ws_size,
                              hipStream_t stream) {
    const float* x    = (const float*)d_in[0];
    const int*   ei_a = (const int*)d_in[1];
    const int*   ei_b = (const int*)d_in[2];
    const float* W0a = (const float*)d_in[3];
    const float* as0a = (const float*)d_in[4];
    const float* ad0a = (const float*)d_in[5];
    const float* b0a = (const float*)d_in[6];
    const float* W0b = (const float*)d_in[7];
    const float* as0b = (const float*)d_in[8];
    const float* ad0b = (const float*)d_in[9];
    const float* b0b = (const float*)d_in[10];
    const float* W1a = (const float*)d_in[11];
    const float* as1a = (const float*)d_in[12];
    const float* ad1a = (const float*)d_in[13];
    const float* b1a = (const float*)d_in[14];
    const float* W1b = (const float*)d_in[15];
    const float* as1b = (const float*)d_in[16];
    const float* ad1b = (const float*)d_in[17];
    const float* b1b = (const float*)d_in[18];
    const float* Wout = (const float*)d_in[19];
    const float* bout = (const float*)d_in[20];
    float* out = (float*)d_out;

    // workspace carve
    unsigned short* h_ab  = (unsigned short*)d_ws;          // N*512 ushort
    unsigned short* bf_in = h_ab + (size_t)N_NODES * HD2;   // N*256 ushort
    unsigned short* Wt2   = bf_in + (size_t)N_NODES * HD;   // 512*256 ushort
    float* ssrc8  = (float*)(Wt2 + (size_t)HD2 * KDIM);     // N*8
    float* sdst8  = ssrc8 + (size_t)N_NODES * 8;            // N*8
    float* m8     = sdst8 + (size_t)N_NODES * 8;            // N*8
    float* zr8    = m8 + (size_t)N_NODES * 8;               // N*8
    float* ebuf_a = zr8 + (size_t)N_NODES * 8;              // E*4
    float* ebuf_b = ebuf_a + (size_t)E_EDGES * NH;          // E*4
    int*   ibase  = (int*)(ebuf_b + (size_t)E_EDGES * NH);
    int* deg     = ibase;
    int* cursor  = deg + N_NODES;
    int* rp_a    = cursor + N_NODES;
    int* cs_a    = rp_a + N_NODES + 1;
    int* cd_a    = cs_a + E_EDGES;
    int* rp_b    = cd_a + E_EDGES;
    int* cs_b    = rp_b + N_NODES + 1;
    int* cd_b    = cs_b + E_EDGES;
    int* excl    = cd_b + E_EDGES;
    int* bsums   = excl + N_NODES;

    const size_t NF = (size_t)N_NODES * HD;
    const int nf4_blocks = (int)((NF / 4 + 255) / 256);

    // ---- CSR for both edge types (reused by both layers) ----
    build_csr(ei_a, deg, cursor, rp_a, cs_a, cd_a, excl, bsums, stream);
    build_csr(ei_b, deg, cursor, rp_b, cs_b, cd_b, excl, bsums, stream);

    // ---- layer 0 ----
    convert_bf16_kernel<<<nf4_blocks, 256, 0, stream>>>(x, bf_in, (int)NF);
    run_layer(bf_in, rp_a, cs_a, cd_a, rp_b, cs_b, cd_b, W0a, W0b,
              as0a, ad0a, as0b, ad0b, b0a, b0b, Wt2, h_ab,
              ssrc8, sdst8, m8, zr8, ebuf_a, ebuf_b,
              bf_in, /*leaky=*/1, stream);

    // ---- layer 1 ----
    run_layer(bf_in, rp_a, cs_a, cd_a, rp_b, cs_b, cd_b, W1a, W1b,
              as1a, ad1a, as1b, ad1b, b1a, b1b, Wt2, h_ab,
              ssrc8, sdst8, m8, zr8, ebuf_a, ebuf_b,
              bf_in, /*leaky=*/0, stream);

    // ---- output projection (192 padded cols covers NC=153) ----
    wt_kernel<<<KDIM, 256, 0, stream>>>(Wout, Wt2, NC);
    gemm_a_lds<3><<<(N_NODES + 63) / 64, 256, 0, stream>>>(
        bf_in, Wt2, out, nullptr, bout, N_NODES, NC);
}

// Round 2
// 541.115 us; speedup vs baseline: 1.1320x; 1.1320x over previous
//
#include <hip/hip_runtime.h>
#include <math.h>

#define N_NODES 50000
#define E_EDGES 250000
#define HD 256          // H * D per edge type
#define NH 4
#define DH 64
#define NC 153
#define KDIM 256        // all GEMMs have K = 256
#define HD2 512         // both edge types concatenated

// ---------- fp32 <-> bf16 ----------
__device__ __forceinline__ unsigned short f2bf(float f) {
    unsigned u = __float_as_uint(f);
    u = u + 0x7FFFu + ((u >> 16) & 1u);
    return (unsigned short)(u >> 16);
}
__device__ __forceinline__ float bf2f(unsigned short b) {
    return __uint_as_float(((unsigned)b) << 16);
}

typedef __attribute__((ext_vector_type(8))) short bf16x8;
typedef __attribute__((ext_vector_type(4))) float f32x4;

// ================= K=256 bf16 MFMA GEMM =================
// C[M,Ncols] = A[M,256] @ BT[Ncols,256]^T (+bias), BT zero-padded to 64*gridDim.y rows.
// Block: 256 rows x 64 cols; 4 waves stacked in M share one B tile (64x256, LDS, 32KB,
// XOR-swizzled byte ^= (row&7)<<4 -> bank-uniform ds_read_b128 and staging writes).
// A: ALL 32 fragment loads (4 row-tiles x 8 K-steps) issued up front into registers
// (128 VGPR; accumulators live in AGPRs) -> one global-latency hit per wave, then the
// K-loop is pure LDS+MFMA. This attacks round-0's depth-1 A-prefetch latency bound.
__global__ __launch_bounds__(256) void gemm_k256(
        const unsigned short* __restrict__ A, const unsigned short* __restrict__ BT,
        float* __restrict__ Cf, unsigned short* __restrict__ Cbf,
        const float* __restrict__ bias, int M, int Ncols) {
    __shared__ unsigned short Bs[64 * 256];   // 32 KB, swizzled
    const int tid = threadIdx.x;
    const int lane = tid & 63;
    const int wave = tid >> 6;
    const int row0 = blockIdx.x * 256 + wave * 64;
    const int col0 = blockIdx.y * 64;
    const int quad = lane >> 4;
    const int l16 = lane & 15;

    // ---- issue ALL A loads first (32 x global_load_dwordx4, 8-deep pipeline) ----
    size_t a_off[4];
    #pragma unroll
    for (int mt = 0; mt < 4; mt++) {
        int gr = row0 + mt * 16 + l16;
        if (gr >= M) gr = M - 1;
        a_off[mt] = (size_t)gr * KDIM + quad * 8;
    }
    bf16x8 a_all[4][8];
    #pragma unroll
    for (int kk = 0; kk < 8; kk++)
        #pragma unroll
        for (int mt = 0; mt < 4; mt++)
            a_all[mt][kk] = *(const bf16x8*)&A[a_off[mt] + kk * 32];

    // ---- stage B(col0..col0+63, 0..255) -> LDS with XOR swizzle ----
    #pragma unroll
    for (int j = 0; j < 8; j++) {
        const int c = tid + 256 * j;         // 16B chunk id (2048 total)
        const int r = c >> 5;                // B row (0..63), 32 chunks/row
        const int kb = (c & 31) << 4;        // byte offset within 512B row
        const uint4 v = *(const uint4*)((const char*)BT +
                            (size_t)(col0 + r) * 512 + kb);
        *(uint4*)((char*)Bs + r * 512 + (kb ^ ((r & 7) << 4))) = v;
    }
    __syncthreads();

    f32x4 acc[4][4];
    #pragma unroll
    for (int i = 0; i < 4; i++)
        #pragma unroll
        for (int j = 0; j < 4; j++) acc[i][j] = (f32x4)0.f;

    // per-lane B LDS addressing: row = nt*16 + l16, byte = (kk*64 | quad*16) ^ ((l16&7)<<4)
    const char* Bsc = (const char*)Bs;
    const int bbase = l16 * 512 + ((quad * 16) ^ ((l16 & 7) << 4));

    bf16x8 b_cur[4], b_nxt[4];
    #pragma unroll
    for (int nt = 0; nt < 4; nt++)
        b_cur[nt] = *(const bf16x8*)(Bsc + nt * 16 * 512 + bbase);

    #pragma unroll
    for (int kk = 0; kk < 8; kk++) {
        if (kk < 7) {
            #pragma unroll
            for (int nt = 0; nt < 4; nt++)
                b_nxt[nt] = *(const bf16x8*)(Bsc + nt * 16 * 512 +
                                (bbase ^ ((kk + 1) * 64)));
        }
        #pragma unroll
        for (int mt = 0; mt < 4; mt++)
            #pragma unroll
            for (int nt = 0; nt < 4; nt++)
                acc[mt][nt] = __builtin_amdgcn_mfma_f32_16x16x32_bf16(
                                  a_all[mt][kk], b_cur[nt], acc[mt][nt], 0, 0, 0);
        #pragma unroll
        for (int nt = 0; nt < 4; nt++) b_cur[nt] = b_nxt[nt];
    }

    #pragma unroll
    for (int mt = 0; mt < 4; mt++) {
        #pragma unroll
        for (int nt = 0; nt < 4; nt++) {
            const int n = col0 + nt * 16 + l16;
            if (n >= Ncols) continue;
            const float bv = bias ? bias[n] : 0.f;
            #pragma unroll
            for (int r = 0; r < 4; r++) {
                const int m = row0 + mt * 16 + quad * 4 + r;
                if (m < M) {
                    const float v = acc[mt][nt][r] + bv;
                    if (Cf)  Cf[(size_t)m * Ncols + n] = v;
                    if (Cbf) Cbf[(size_t)m * Ncols + n] = f2bf(v);
                }
            }
        }
    }
}

// ---------- fp32 -> bf16 conversion (vectorized) ----------
__global__ __launch_bounds__(256) void convert_bf16_kernel(
        const float* __restrict__ in, unsigned short* __restrict__ out, int n) {
    const int i = (blockIdx.x * 256 + threadIdx.x) * 4;
    if (i + 3 < n) {
        const float4 v = *(const float4*)&in[i];
        ushort4 o;
        o.x = f2bf(v.x); o.y = f2bf(v.y); o.z = f2bf(v.z); o.w = f2bf(v.w);
        *(ushort4*)&out[i] = o;
    } else {
        for (int j = i; j < n; j++) out[j] = f2bf(in[j]);
    }
}

// ---------- dual weight transpose+convert: Wa,Wb[K,256] -> Wt[512,K] bf16 ----------
__global__ __launch_bounds__(256) void wt2_kernel(
        const float* __restrict__ Wa, const float* __restrict__ Wb,
        unsigned short* __restrict__ Wt) {
    const int idx = blockIdx.x * 256 + threadIdx.x;
    const int n = idx >> 8, k = idx & 255;
    Wt[idx] = (n < HD) ? f2bf(Wa[(size_t)k * HD + n])
                       : f2bf(Wb[(size_t)k * HD + (n - HD)]);
}

// ---------- single weight transpose+convert with zero-pad to 256 rows ----------
__global__ __launch_bounds__(256) void wt_kernel(
        const float* __restrict__ W, unsigned short* __restrict__ Wt, int Nc) {
    const int idx = blockIdx.x * 256 + threadIdx.x;
    const int n = idx >> 8, k = idx & 255;
    Wt[idx] = (n < Nc) ? f2bf(W[(size_t)k * Nc + n]) : (unsigned short)0;
}

// ---------- CSR construction ----------
__global__ __launch_bounds__(256) void zero_int_kernel(int* __restrict__ p, int n) {
    const int i = blockIdx.x * 256 + threadIdx.x;
    if (i < n) p[i] = 0;
}

__global__ __launch_bounds__(256) void hist_kernel(
        const int* __restrict__ ei, int* __restrict__ deg) {
    const int e = blockIdx.x * 256 + threadIdx.x;
    if (e < E_EDGES) atomicAdd(&deg[ei[E_EDGES + e]], 1);
}

__global__ __launch_bounds__(1024) void scan_local_kernel(
        const int* __restrict__ deg, int* __restrict__ excl,
        int* __restrict__ bsums, int n) {
    __shared__ int wsum[16];
    const int i = blockIdx.x * 1024 + threadIdx.x;
    const int lane = threadIdx.x & 63;
    const int wid = threadIdx.x >> 6;
    const int v = (i < n) ? deg[i] : 0;
    int s = v;
    #pragma unroll
    for (int off = 1; off < 64; off <<= 1) {
        const int t = __shfl_up(s, off);
        if (lane >= off) s += t;
    }
    if (lane == 63) wsum[wid] = s;
    __syncthreads();
    if (wid == 0) {
        int wv = (lane < 16) ? wsum[lane] : 0;
        #pragma unroll
        for (int off = 1; off < 16; off <<= 1) {
            const int t = __shfl_up(wv, off);
            if (lane >= off) wv += t;
        }
        if (lane < 16) wsum[lane] = wv;
    }
    __syncthreads();
    const int woff = (wid > 0) ? wsum[wid - 1] : 0;
    if (i < n) excl[i] = s - v + woff;
    if (threadIdx.x == 1023) bsums[blockIdx.x] = wsum[15];
}

__global__ __launch_bounds__(64) void scan_bsums_kernel(
        int* __restrict__ bsums, int* __restrict__ row_ptr, int nb, int n) {
    const int lane = threadIdx.x;
    const int v = (lane < nb) ? bsums[lane] : 0;
    int s = v;
    #pragma unroll
    for (int off = 1; off < 64; off <<= 1) {
        const int t = __shfl_up(s, off);
        if (lane >= off) s += t;
    }
    if (lane < nb) bsums[lane] = s - v;
    if (lane == 63) row_ptr[n] = s;
}

__global__ __launch_bounds__(256) void scan_add_kernel(
        const int* __restrict__ excl, const int* __restrict__ bsums,
        int* __restrict__ row_ptr, int* __restrict__ cursor, int n) {
    const int i = blockIdx.x * 256 + threadIdx.x;
    if (i >= n) return;
    const int v = excl[i] + bsums[i >> 10];
    row_ptr[i] = v;
    cursor[i]  = v;
}

__global__ __launch_bounds__(256) void scatter_kernel(
        const int* __restrict__ ei, int* __restrict__ cursor,
        int* __restrict__ col_src, int* __restrict__ col_dst) {
    const int e = blockIdx.x * 256 + threadIdx.x;
    if (e >= E_EDGES) return;
    const int src = ei[e], dst = ei[E_EDGES + e];
    const int pos = atomicAdd(&cursor[dst], 1);
    col_src[pos] = src;
    col_dst[pos] = dst;
}

// ---------- per-node attention scores for BOTH etypes ----------
__global__ __launch_bounds__(256) void scores2_kernel(
        const unsigned short* __restrict__ h_ab,
        const float* __restrict__ as_a, const float* __restrict__ ad_a,
        const float* __restrict__ as_b, const float* __restrict__ ad_b,
        float* __restrict__ ssrc8, float* __restrict__ sdst8) {
    const int node = blockIdx.x * 4 + (threadIdx.x >> 6);
    const int lane = threadIdx.x & 63;
    if (node >= N_NODES) return;
    const size_t base = (size_t)node * HD2 + lane * 4;

    const ushort4 ha = *(const ushort4*)&h_ab[base];
    const ushort4 hb = *(const ushort4*)&h_ab[base + HD];
    const float4 asa = *(const float4*)&as_a[lane * 4];
    const float4 ada = *(const float4*)&ad_a[lane * 4];
    const float4 asb = *(const float4*)&as_b[lane * 4];
    const float4 adb = *(const float4*)&ad_b[lane * 4];
    const float a0 = bf2f(ha.x), a1 = bf2f(ha.y), a2 = bf2f(ha.z), a3 = bf2f(ha.w);
    const float b0 = bf2f(hb.x), b1 = bf2f(hb.y), b2 = bf2f(hb.z), b3 = bf2f(hb.w);

    float rsa = a0 * asa.x + a1 * asa.y + a2 * asa.z + a3 * asa.w;
    float rda = a0 * ada.x + a1 * ada.y + a2 * ada.z + a3 * ada.w;
    float rsb = b0 * asb.x + b1 * asb.y + b2 * asb.z + b3 * asb.w;
    float rdb = b0 * adb.x + b1 * adb.y + b2 * adb.z + b3 * adb.w;
    #pragma unroll
    for (int off = 1; off < 16; off <<= 1) {
        rsa += __shfl_xor(rsa, off);
        rda += __shfl_xor(rda, off);
        rsb += __shfl_xor(rsb, off);
        rdb += __shfl_xor(rdb, off);
    }
    if ((lane & 15) == 0) {
        const int hh = lane >> 4;
        ssrc8[node * 8 + 0 + hh] = rsa;
        sdst8[node * 8 + 0 + hh] = rda;
        ssrc8[node * 8 + 4 + hh] = rsb;
        sdst8[node * 8 + 4 + hh] = rdb;
    }
}

// ---------- S1: per (node,etype,head) thread computes m and 1/(z+eps) ----------
__global__ __launch_bounds__(256) void seg_mz8_kernel(
        const int* __restrict__ rp_a, const int* __restrict__ cs_a,
        const int* __restrict__ rp_b, const int* __restrict__ cs_b,
        const float* __restrict__ ssrc8, const float* __restrict__ sdst8,
        float* __restrict__ m8, float* __restrict__ zr8) {
    const int t = blockIdx.x * 256 + threadIdx.x;
    if (t >= N_NODES * 8) return;
    const int node = t >> 3;
    const int r8 = t & 7;
    const int et = r8 >> 2;
    const int* rp = et ? rp_b : rp_a;
    const int* cs = et ? cs_b : cs_a;
    const int beg = rp[node], end = rp[node + 1];
    const float sd = sdst8[t];
    float m = -INFINITY;
    for (int e = beg; e < end; e++) {
        float s = ssrc8[cs[e] * 8 + r8] + sd;
        s = (s >= 0.f) ? s : 0.2f * s;
        m = fmaxf(m, s);
    }
    float z = 0.f;
    for (int e = beg; e < end; e++) {
        float s = ssrc8[cs[e] * 8 + r8] + sd;
        s = (s >= 0.f) ? s : 0.2f * s;
        z += expf(s - m);
    }
    m8[t]  = m;
    zr8[t] = 1.f / (z + 1e-16f);
}

// ---------- S2: per (edge,head) alpha in CSR order, one etype ----------
__global__ __launch_bounds__(256) void alpha_kernel(
        const int* __restrict__ cs, const int* __restrict__ cd,
        const float* __restrict__ ssrc8, const float* __restrict__ sdst8,
        const float* __restrict__ m8, const float* __restrict__ zr8,
        float* __restrict__ ebuf, int et) {
    const int t = blockIdx.x * 256 + threadIdx.x;
    if (t >= E_EDGES * NH) return;
    const int pos = t >> 2, hh = t & 3;
    const int r8 = et * 4 + hh;
    const int src = cs[pos], dst = cd[pos];
    float s = ssrc8[src * 8 + r8] + sdst8[dst * 8 + r8];
    s = (s >= 0.f) ? s : 0.2f * s;
    ebuf[t] = expf(s - m8[dst * 8 + r8]) * zr8[dst * 8 + r8];
}

// ---------- S3: aggregation + fused epilogue (bias, leaky, bf16 write) ----------
__global__ __launch_bounds__(256) void aggregate_both_kernel(
        const int* __restrict__ rp_a, const int* __restrict__ cs_a,
        const int* __restrict__ rp_b, const int* __restrict__ cs_b,
        const unsigned short* __restrict__ h_ab,
        const float* __restrict__ ebuf_a, const float* __restrict__ ebuf_b,
        const float* __restrict__ b1, const float* __restrict__ b2,
        unsigned short* __restrict__ out_bf, int do_leaky) {
    const int node = blockIdx.x * 4 + (threadIdx.x >> 6);
    const int lane = threadIdx.x & 63;
    if (node >= N_NODES) return;
    const int hh = lane >> 4;
    const int c4 = lane * 4;

    float4 a = make_float4(0.f, 0.f, 0.f, 0.f);

    #pragma unroll
    for (int et = 0; et < 2; et++) {
        const int* rp = et ? rp_b : rp_a;
        const int* cs = et ? cs_b : cs_a;
        const float* eb = et ? ebuf_b : ebuf_a;
        const size_t hoff = et ? (size_t)HD : 0;
        const int beg = rp[node], end = rp[node + 1];
        int e = beg;
        for (; e + 3 < end; e += 4) {
            const int s0 = cs[e + 0], s1 = cs[e + 1],
                      s2 = cs[e + 2], s3 = cs[e + 3];
            const float al0 = eb[(e + 0) * NH + hh];
            const float al1 = eb[(e + 1) * NH + hh];
            const float al2 = eb[(e + 2) * NH + hh];
            const float al3 = eb[(e + 3) * NH + hh];
            const ushort4 h0 = *(const ushort4*)&h_ab[(size_t)s0 * HD2 + hoff + c4];
            const ushort4 h1 = *(const ushort4*)&h_ab[(size_t)s1 * HD2 + hoff + c4];
            const ushort4 h2 = *(const ushort4*)&h_ab[(size_t)s2 * HD2 + hoff + c4];
            const ushort4 h3 = *(const ushort4*)&h_ab[(size_t)s3 * HD2 + hoff + c4];
            a.x = fmaf(al0, bf2f(h0.x), a.x); a.y = fmaf(al0, bf2f(h0.y), a.y);
            a.z = fmaf(al0, bf2f(h0.z), a.z); a.w = fmaf(al0, bf2f(h0.w), a.w);
            a.x = fmaf(al1, bf2f(h1.x), a.x); a.y = fmaf(al1, bf2f(h1.y), a.y);
            a.z = fmaf(al1, bf2f(h1.z), a.z); a.w = fmaf(al1, bf2f(h1.w), a.w);
            a.x = fmaf(al2, bf2f(h2.x), a.x); a.y = fmaf(al2, bf2f(h2.y), a.y);
            a.z = fmaf(al2, bf2f(h2.z), a.z); a.w = fmaf(al2, bf2f(h2.w), a.w);
            a.x = fmaf(al3, bf2f(h3.x), a.x); a.y = fmaf(al3, bf2f(h3.y), a.y);
            a.z = fmaf(al3, bf2f(h3.z), a.z); a.w = fmaf(al3, bf2f(h3.w), a.w);
        }
        for (; e < end; e++) {
            const int src = cs[e];
            const float al = eb[e * NH + hh];
            const ushort4 hv = *(const ushort4*)&h_ab[(size_t)src * HD2 + hoff + c4];
            a.x = fmaf(al, bf2f(hv.x), a.x);
            a.y = fmaf(al, bf2f(hv.y), a.y);
            a.z = fmaf(al, bf2f(hv.z), a.z);
            a.w = fmaf(al, bf2f(hv.w), a.w);
        }
    }

    const float4 bv1 = *(const float4*)&b1[c4];
    const float4 bv2 = *(const float4*)&b2[c4];
    float4 v;
    v.x = a.x + bv1.x + bv2.x;
    v.y = a.y + bv1.y + bv2.y;
    v.z = a.z + bv1.z + bv2.z;
    v.w = a.w + bv1.w + bv2.w;
    if (do_leaky) {
        v.x = (v.x >= 0.f) ? v.x : 0.01f * v.x;
        v.y = (v.y >= 0.f) ? v.y : 0.01f * v.y;
        v.z = (v.z >= 0.f) ? v.z : 0.01f * v.z;
        v.w = (v.w >= 0.f) ? v.w : 0.01f * v.w;
    }
    ushort4 o;
    o.x = f2bf(v.x); o.y = f2bf(v.y); o.z = f2bf(v.z); o.w = f2bf(v.w);
    *(ushort4*)&out_bf[(size_t)node * HD + c4] = o;
}

// ---------- host-side helpers ----------
static void run_layer(const unsigned short* a_bf,
                      const int* rp_a, const int* cs_a, const int* cd_a,
                      const int* rp_b, const int* cs_b, const int* cd_b,
                      const float* Wa, const float* Wb,
                      const float* as_a, const float* ad_a,
                      const float* as_b, const float* ad_b,
                      const float* b1, const float* b2,
                      unsigned short* Wt2, unsigned short* h_ab,
                      float* ssrc8, float* sdst8, float* m8, float* zr8,
                      float* ebuf_a, float* ebuf_b,
                      unsigned short* out_bf, int do_leaky,
                      hipStream_t stream) {
    wt2_kernel<<<HD2, 256, 0, stream>>>(Wa, Wb, Wt2);
    dim3 ggrid((N_NODES + 255) / 256, HD2 / 64);
    gemm_k256<<<ggrid, 256, 0, stream>>>(a_bf, Wt2, nullptr, h_ab, nullptr,
                                         N_NODES, HD2);
    scores2_kernel<<<(N_NODES + 3) / 4, 256, 0, stream>>>(
        h_ab, as_a, ad_a, as_b, ad_b, ssrc8, sdst8);
    seg_mz8_kernel<<<(N_NODES * 8 + 255) / 256, 256, 0, stream>>>(
        rp_a, cs_a, rp_b, cs_b, ssrc8, sdst8, m8, zr8);
    const int ab = (E_EDGES * NH + 255) / 256;
    alpha_kernel<<<ab, 256, 0, stream>>>(cs_a, cd_a, ssrc8, sdst8, m8, zr8, ebuf_a, 0);
    alpha_kernel<<<ab, 256, 0, stream>>>(cs_b, cd_b, ssrc8, sdst8, m8, zr8, ebuf_b, 1);
    aggregate_both_kernel<<<(N_NODES + 3) / 4, 256, 0, stream>>>(
        rp_a, cs_a, rp_b, cs_b, h_ab, ebuf_a, ebuf_b, b1, b2, out_bf, do_leaky);
}

static void build_csr(const int* ei, int* deg, int* cursor, int* row_ptr,
                      int* col_src, int* col_dst, int* excl, int* bsums,
                      hipStream_t stream) {
    const int nb  = (N_NODES + 255) / 256;
    const int eb  = (E_EDGES + 255) / 256;
    const int sb  = (N_NODES + 1023) / 1024;
    zero_int_kernel<<<nb, 256, 0, stream>>>(deg, N_NODES);
    hist_kernel<<<eb, 256, 0, stream>>>(ei, deg);
    scan_local_kernel<<<sb, 1024, 0, stream>>>(deg, excl, bsums, N_NODES);
    scan_bsums_kernel<<<1, 64, 0, stream>>>(bsums, row_ptr, sb, N_NODES);
    scan_add_kernel<<<nb, 256, 0, stream>>>(excl, bsums, row_ptr, cursor, N_NODES);
    scatter_kernel<<<eb, 256, 0, stream>>>(ei, cursor, col_src, col_dst);
}

extern "C" void kernel_launch(void* const* d_in, const int* in_sizes, int n_in,
                              void* d_out, int out_size, void* d_ws, size_t ws_size,
                              hipStream_t stream) {
    const float* x    = (const float*)d_in[0];
    const int*   ei_a = (const int*)d_in[1];
    const int*   ei_b = (const int*)d_in[2];
    const float* W0a = (const float*)d_in[3];
    const float* as0a = (const float*)d_in[4];
    const float* ad0a = (const float*)d_in[5];
    const float* b0a = (const float*)d_in[6];
    const float* W0b = (const float*)d_in[7];
    const float* as0b = (const float*)d_in[8];
    const float* ad0b = (const float*)d_in[9];
    const float* b0b = (const float*)d_in[10];
    const float* W1a = (const float*)d_in[11];
    const float* as1a = (const float*)d_in[12];
    const float* ad1a = (const float*)d_in[13];
    const float* b1a = (const float*)d_in[14];
    const float* W1b = (const float*)d_in[15];
    const float* as1b = (const float*)d_in[16];
    const float* ad1b = (const float*)d_in[17];
    const float* b1b = (const float*)d_in[18];
    const float* Wout = (const float*)d_in[19];
    const float* bout = (const float*)d_in[20];
    float* out = (float*)d_out;

    // workspace carve
    unsigned short* h_ab  = (unsigned short*)d_ws;          // N*512 ushort
    unsigned short* bf_in = h_ab + (size_t)N_NODES * HD2;   // N*256 ushort
    unsigned short* Wt2   = bf_in + (size_t)N_NODES * HD;   // 512*256 ushort
    float* ssrc8  = (float*)(Wt2 + (size_t)HD2 * KDIM);     // N*8
    float* sdst8  = ssrc8 + (size_t)N_NODES * 8;            // N*8
    float* m8     = sdst8 + (size_t)N_NODES * 8;            // N*8
    float* zr8    = m8 + (size_t)N_NODES * 8;               // N*8
    float* ebuf_a = zr8 + (size_t)N_NODES * 8;              // E*4
    float* ebuf_b = ebuf_a + (size_t)E_EDGES * NH;          // E*4
    int*   ibase  = (int*)(ebuf_b + (size_t)E_EDGES * NH);
    int* deg     = ibase;
    int* cursor  = deg + N_NODES;
    int* rp_a    = cursor + N_NODES;
    int* cs_a    = rp_a + N_NODES + 1;
    int* cd_a    = cs_a + E_EDGES;
    int* rp_b    = cd_a + E_EDGES;
    int* cs_b    = rp_b + N_NODES + 1;
    int* cd_b    = cs_b + E_EDGES;
    int* excl    = cd_b + E_EDGES;
    int* bsums   = excl + N_NODES;

    const size_t NF = (size_t)N_NODES * HD;
    const int nf4_blocks = (int)((NF / 4 + 255) / 256);

    // ---- CSR for both edge types (reused by both layers) ----
    build_csr(ei_a, deg, cursor, rp_a, cs_a, cd_a, excl, bsums, stream);
    build_csr(ei_b, deg, cursor, rp_b, cs_b, cd_b, excl, bsums, stream);

    // ---- layer 0 ----
    convert_bf16_kernel<<<nf4_blocks, 256, 0, stream>>>(x, bf_in, (int)NF);
    run_layer(bf_in, rp_a, cs_a, cd_a, rp_b, cs_b, cd_b, W0a, W0b,
              as0a, ad0a, as0b, ad0b, b0a, b0b, Wt2, h_ab,
              ssrc8, sdst8, m8, zr8, ebuf_a, ebuf_b,
              bf_in, /*leaky=*/1, stream);

    // ---- layer 1 ----
    run_layer(bf_in, rp_a, cs_a, cd_a, rp_b, cs_b, cd_b, W1a, W1b,
              as1a, ad1a, as1b, ad1b, b1a, b1b, Wt2, h_ab,
              ssrc8, sdst8, m8, zr8, ebuf_a, ebuf_b,
              bf_in, /*leaky=*/0, stream);

    // ---- output projection ----
    wt_kernel<<<KDIM, 256, 0, stream>>>(Wout, Wt2, NC);
    dim3 ogrid((N_NODES + 255) / 256, 3);   // 3 x 64 cols covers NC=153
    gemm_k256<<<ogrid, 256, 0, stream>>>(bf_in, Wt2, out, nullptr, bout,
                                         N_NODES, NC);
}

// Round 3
// 514.177 us; speedup vs baseline: 1.1913x; 1.0524x over previous
//
#include <hip/hip_runtime.h>
#include <math.h>

#define N_NODES 50000
#define E_EDGES 250000
#define HD 256          // H * D per edge type
#define NH 4
#define DH 64
#define NC 153
#define KDIM 256        // all GEMMs have K = 256
#define HD2 512         // both edge types concatenated

// ---------- fp32 <-> bf16 ----------
__device__ __forceinline__ unsigned short f2bf(float f) {
    unsigned u = __float_as_uint(f);
    u = u + 0x7FFFu + ((u >> 16) & 1u);
    return (unsigned short)(u >> 16);
}
__device__ __forceinline__ float bf2f(unsigned short b) {
    return __uint_as_float(((unsigned)b) << 16);
}

typedef __attribute__((ext_vector_type(8))) short bf16x8;
typedef __attribute__((ext_vector_type(4))) float f32x4;

// ================= K=256 bf16 MFMA GEMM =================
// C[M,Ncols] = A[M,256] @ BT[Ncols,256]^T (+bias), BT zero-padded to 64*gridDim.x rows.
// Block: 256 rows x 64 cols; 4 waves stacked in M share one B tile (64x256 bf16, 32KB
// LDS, XOR-swizzled byte ^= (row&7)<<4 -> 5 blocks/CU residency, conflict-free-ish reads).
// A streamed from global with depth-1 register prefetch (round-0 pipeline, known-good).
// GRID: blockIdx.x = col-block (FASTEST), blockIdx.y = row-block -> consecutive blocks
// share the same 128KB A row-panel across the 8 col-blocks => A read from HBM once,
// re-served from L2 (round-2 showed row-fastest order re-streams A 8x, FETCH 94MB).
__global__ __launch_bounds__(256) void gemm_k256(
        const unsigned short* __restrict__ A, const unsigned short* __restrict__ BT,
        float* __restrict__ Cf, unsigned short* __restrict__ Cbf,
        const float* __restrict__ bias, int M, int Ncols) {
    __shared__ unsigned short Bs[64 * 256];   // 32 KB, swizzled
    const int tid = threadIdx.x;
    const int lane = tid & 63;
    const int wave = tid >> 6;
    const int row0 = blockIdx.y * 256 + wave * 64;
    const int col0 = blockIdx.x * 64;
    const int quad = lane >> 4;
    const int l16 = lane & 15;

    // ---- stage B(col0..col0+63, 0..255) -> LDS with XOR swizzle ----
    #pragma unroll
    for (int j = 0; j < 8; j++) {
        const int c = tid + 256 * j;         // 16B chunk id (2048 total)
        const int r = c >> 5;                // B row (0..63), 32 chunks/row
        const int kb = (c & 31) << 4;        // byte offset within 512B row
        const uint4 v = *(const uint4*)((const char*)BT +
                            (size_t)(col0 + r) * 512 + kb);
        *(uint4*)((char*)Bs + r * 512 + (kb ^ ((r & 7) << 4))) = v;
    }
    __syncthreads();

    f32x4 acc[4][4];
    #pragma unroll
    for (int i = 0; i < 4; i++)
        #pragma unroll
        for (int j = 0; j < 4; j++) acc[i][j] = (f32x4)0.f;

    size_t a_off[4];
    #pragma unroll
    for (int mt = 0; mt < 4; mt++) {
        int gr = row0 + mt * 16 + l16;
        if (gr >= M) gr = M - 1;
        a_off[mt] = (size_t)gr * KDIM + quad * 8;
    }
    // B fragment addressing: row = nt*16+l16, byte = (kk*64 + quad*16) ^ ((l16&7)<<4)
    // (kk*64 and quad*16 occupy disjoint bits -> '+' == '^', fold into one XOR base)
    const char* Bsc = (const char*)Bs;
    const int bbase = l16 * 512 + ((quad * 16) ^ ((l16 & 7) << 4));

    bf16x8 a_cur[4], b_cur[4], a_nxt[4], b_nxt[4];
    #pragma unroll
    for (int t = 0; t < 4; t++) {
        a_cur[t] = *(const bf16x8*)&A[a_off[t]];
        b_cur[t] = *(const bf16x8*)(Bsc + t * 16 * 512 + bbase);
    }

    #pragma unroll
    for (int kk = 0; kk < 8; kk++) {
        if (kk < 7) {
            #pragma unroll
            for (int t = 0; t < 4; t++) {
                a_nxt[t] = *(const bf16x8*)&A[a_off[t] + (kk + 1) * 32];
                b_nxt[t] = *(const bf16x8*)(Bsc + t * 16 * 512 +
                                (bbase ^ ((kk + 1) * 64)));
            }
        }
        #pragma unroll
        for (int mt = 0; mt < 4; mt++)
            #pragma unroll
            for (int nt = 0; nt < 4; nt++)
                acc[mt][nt] = __builtin_amdgcn_mfma_f32_16x16x32_bf16(
                                  a_cur[mt], b_cur[nt], acc[mt][nt], 0, 0, 0);
        #pragma unroll
        for (int t = 0; t < 4; t++) { a_cur[t] = a_nxt[t]; b_cur[t] = b_nxt[t]; }
    }

    #pragma unroll
    for (int mt = 0; mt < 4; mt++) {
        #pragma unroll
        for (int nt = 0; nt < 4; nt++) {
            const int n = col0 + nt * 16 + l16;
            if (n >= Ncols) continue;
            const float bv = bias ? bias[n] : 0.f;
            #pragma unroll
            for (int r = 0; r < 4; r++) {
                const int m = row0 + mt * 16 + quad * 4 + r;
                if (m < M) {
                    const float v = acc[mt][nt][r] + bv;
                    if (Cf)  Cf[(size_t)m * Ncols + n] = v;
                    if (Cbf) Cbf[(size_t)m * Ncols + n] = f2bf(v);
                }
            }
        }
    }
}

// ---------- fp32 -> bf16 conversion (vectorized) ----------
__global__ __launch_bounds__(256) void convert_bf16_kernel(
        const float* __restrict__ in, unsigned short* __restrict__ out, int n) {
    const int i = (blockIdx.x * 256 + threadIdx.x) * 4;
    if (i + 3 < n) {
        const float4 v = *(const float4*)&in[i];
        ushort4 o;
        o.x = f2bf(v.x); o.y = f2bf(v.y); o.z = f2bf(v.z); o.w = f2bf(v.w);
        *(ushort4*)&out[i] = o;
    } else {
        for (int j = i; j < n; j++) out[j] = f2bf(in[j]);
    }
}

// ---------- dual weight transpose+convert: Wa,Wb[K,256] -> Wt[512,K] bf16 ----------
__global__ __launch_bounds__(256) void wt2_kernel(
        const float* __restrict__ Wa, const float* __restrict__ Wb,
        unsigned short* __restrict__ Wt) {
    const int idx = blockIdx.x * 256 + threadIdx.x;
    const int n = idx >> 8, k = idx & 255;
    Wt[idx] = (n < HD) ? f2bf(Wa[(size_t)k * HD + n])
                       : f2bf(Wb[(size_t)k * HD + (n - HD)]);
}

// ---------- single weight transpose+convert with zero-pad to 256 rows ----------
__global__ __launch_bounds__(256) void wt_kernel(
        const float* __restrict__ W, unsigned short* __restrict__ Wt, int Nc) {
    const int idx = blockIdx.x * 256 + threadIdx.x;
    const int n = idx >> 8, k = idx & 255;
    Wt[idx] = (n < Nc) ? f2bf(W[(size_t)k * Nc + n]) : (unsigned short)0;
}

// ---------- CSR construction ----------
__global__ __launch_bounds__(256) void zero_int_kernel(int* __restrict__ p, int n) {
    const int i = blockIdx.x * 256 + threadIdx.x;
    if (i < n) p[i] = 0;
}

__global__ __launch_bounds__(256) void hist_kernel(
        const int* __restrict__ ei, int* __restrict__ deg) {
    const int e = blockIdx.x * 256 + threadIdx.x;
    if (e < E_EDGES) atomicAdd(&deg[ei[E_EDGES + e]], 1);
}

__global__ __launch_bounds__(1024) void scan_local_kernel(
        const int* __restrict__ deg, int* __restrict__ excl,
        int* __restrict__ bsums, int n) {
    __shared__ int wsum[16];
    const int i = blockIdx.x * 1024 + threadIdx.x;
    const int lane = threadIdx.x & 63;
    const int wid = threadIdx.x >> 6;
    const int v = (i < n) ? deg[i] : 0;
    int s = v;
    #pragma unroll
    for (int off = 1; off < 64; off <<= 1) {
        const int t = __shfl_up(s, off);
        if (lane >= off) s += t;
    }
    if (lane == 63) wsum[wid] = s;
    __syncthreads();
    if (wid == 0) {
        int wv = (lane < 16) ? wsum[lane] : 0;
        #pragma unroll
        for (int off = 1; off < 16; off <<= 1) {
            const int t = __shfl_up(wv, off);
            if (lane >= off) wv += t;
        }
        if (lane < 16) wsum[lane] = wv;
    }
    __syncthreads();
    const int woff = (wid > 0) ? wsum[wid - 1] : 0;
    if (i < n) excl[i] = s - v + woff;
    if (threadIdx.x == 1023) bsums[blockIdx.x] = wsum[15];
}

__global__ __launch_bounds__(64) void scan_bsums_kernel(
        int* __restrict__ bsums, int* __restrict__ row_ptr, int nb, int n) {
    const int lane = threadIdx.x;
    const int v = (lane < nb) ? bsums[lane] : 0;
    int s = v;
    #pragma unroll
    for (int off = 1; off < 64; off <<= 1) {
        const int t = __shfl_up(s, off);
        if (lane >= off) s += t;
    }
    if (lane < nb) bsums[lane] = s - v;
    if (lane == 63) row_ptr[n] = s;
}

__global__ __launch_bounds__(256) void scan_add_kernel(
        const int* __restrict__ excl, const int* __restrict__ bsums,
        int* __restrict__ row_ptr, int* __restrict__ cursor, int n) {
    const int i = blockIdx.x * 256 + threadIdx.x;
    if (i >= n) return;
    const int v = excl[i] + bsums[i >> 10];
    row_ptr[i] = v;
    cursor[i]  = v;
}

__global__ __launch_bounds__(256) void scatter_kernel(
        const int* __restrict__ ei, int* __restrict__ cursor,
        int* __restrict__ col_src, int* __restrict__ col_dst) {
    const int e = blockIdx.x * 256 + threadIdx.x;
    if (e >= E_EDGES) return;
    const int src = ei[e], dst = ei[E_EDGES + e];
    const int pos = atomicAdd(&cursor[dst], 1);
    col_src[pos] = src;
    col_dst[pos] = dst;
}

// ---------- per-node attention scores for BOTH etypes ----------
__global__ __launch_bounds__(256) void scores2_kernel(
        const unsigned short* __restrict__ h_ab,
        const float* __restrict__ as_a, const float* __restrict__ ad_a,
        const float* __restrict__ as_b, const float* __restrict__ ad_b,
        float* __restrict__ ssrc8, float* __restrict__ sdst8) {
    const int node = blockIdx.x * 4 + (threadIdx.x >> 6);
    const int lane = threadIdx.x & 63;
    if (node >= N_NODES) return;
    const size_t base = (size_t)node * HD2 + lane * 4;

    const ushort4 ha = *(const ushort4*)&h_ab[base];
    const ushort4 hb = *(const ushort4*)&h_ab[base + HD];
    const float4 asa = *(const float4*)&as_a[lane * 4];
    const float4 ada = *(const float4*)&ad_a[lane * 4];
    const float4 asb = *(const float4*)&as_b[lane * 4];
    const float4 adb = *(const float4*)&ad_b[lane * 4];
    const float a0 = bf2f(ha.x), a1 = bf2f(ha.y), a2 = bf2f(ha.z), a3 = bf2f(ha.w);
    const float b0 = bf2f(hb.x), b1 = bf2f(hb.y), b2 = bf2f(hb.z), b3 = bf2f(hb.w);

    float rsa = a0 * asa.x + a1 * asa.y + a2 * asa.z + a3 * asa.w;
    float rda = a0 * ada.x + a1 * ada.y + a2 * ada.z + a3 * ada.w;
    float rsb = b0 * asb.x + b1 * asb.y + b2 * asb.z + b3 * asb.w;
    float rdb = b0 * adb.x + b1 * adb.y + b2 * adb.z + b3 * adb.w;
    #pragma unroll
    for (int off = 1; off < 16; off <<= 1) {
        rsa += __shfl_xor(rsa, off);
        rda += __shfl_xor(rda, off);
        rsb += __shfl_xor(rsb, off);
        rdb += __shfl_xor(rdb, off);
    }
    if ((lane & 15) == 0) {
        const int hh = lane >> 4;
        ssrc8[node * 8 + 0 + hh] = rsa;
        sdst8[node * 8 + 0 + hh] = rda;
        ssrc8[node * 8 + 4 + hh] = rsb;
        sdst8[node * 8 + 4 + hh] = rdb;
    }
}

// ---------- S1: per (node,etype,head) thread computes m and 1/(z+eps) ----------
__global__ __launch_bounds__(256) void seg_mz8_kernel(
        const int* __restrict__ rp_a, const int* __restrict__ cs_a,
        const int* __restrict__ rp_b, const int* __restrict__ cs_b,
        const float* __restrict__ ssrc8, const float* __restrict__ sdst8,
        float* __restrict__ m8, float* __restrict__ zr8) {
    const int t = blockIdx.x * 256 + threadIdx.x;
    if (t >= N_NODES * 8) return;
    const int node = t >> 3;
    const int r8 = t & 7;
    const int et = r8 >> 2;
    const int* rp = et ? rp_b : rp_a;
    const int* cs = et ? cs_b : cs_a;
    const int beg = rp[node], end = rp[node + 1];
    const float sd = sdst8[t];
    float m = -INFINITY;
    for (int e = beg; e < end; e++) {
        float s = ssrc8[cs[e] * 8 + r8] + sd;
        s = (s >= 0.f) ? s : 0.2f * s;
        m = fmaxf(m, s);
    }
    float z = 0.f;
    for (int e = beg; e < end; e++) {
        float s = ssrc8[cs[e] * 8 + r8] + sd;
        s = (s >= 0.f) ? s : 0.2f * s;
        z += expf(s - m);
    }
    m8[t]  = m;
    zr8[t] = 1.f / (z + 1e-16f);
}

// ---------- S3: aggregation with INLINE alpha + fused epilogue ----------
// Wave per node. alpha = exp(leaky(ssrc[src]+sdst[dst]) - m[dst]) * zr[dst] is
// recomputed per edge per head group (all inputs L2-resident, broadcast reads)
// -> the alpha kernels and the ebuf write+read round-trip are eliminated.
__global__ __launch_bounds__(256) void aggregate_both_kernel(
        const int* __restrict__ rp_a, const int* __restrict__ cs_a,
        const int* __restrict__ rp_b, const int* __restrict__ cs_b,
        const unsigned short* __restrict__ h_ab,
        const float* __restrict__ ssrc8, const float* __restrict__ sdst8,
        const float* __restrict__ m8, const float* __restrict__ zr8,
        const float* __restrict__ b1, const float* __restrict__ b2,
        unsigned short* __restrict__ out_bf, int do_leaky) {
    const int node = blockIdx.x * 4 + (threadIdx.x >> 6);
    const int lane = threadIdx.x & 63;
    if (node >= N_NODES) return;
    const int hh = lane >> 4;
    const int c4 = lane * 4;

    float4 a = make_float4(0.f, 0.f, 0.f, 0.f);

    #pragma unroll
    for (int et = 0; et < 2; et++) {
        const int* rp = et ? rp_b : rp_a;
        const int* cs = et ? cs_b : cs_a;
        const size_t hoff = et ? (size_t)HD : 0;
        const int r8 = et * 4 + hh;
        const float sdv = sdst8[node * 8 + r8];
        const float mm  = m8[node * 8 + r8];
        const float zz  = zr8[node * 8 + r8];
        const int beg = rp[node], end = rp[node + 1];
        int e = beg;
        for (; e + 3 < end; e += 4) {
            const int s0 = cs[e + 0], s1 = cs[e + 1],
                      s2 = cs[e + 2], s3 = cs[e + 3];
            float v0 = ssrc8[s0 * 8 + r8] + sdv; v0 = (v0 >= 0.f) ? v0 : 0.2f * v0;
            float v1 = ssrc8[s1 * 8 + r8] + sdv; v1 = (v1 >= 0.f) ? v1 : 0.2f * v1;
            float v2 = ssrc8[s2 * 8 + r8] + sdv; v2 = (v2 >= 0.f) ? v2 : 0.2f * v2;
            float v3 = ssrc8[s3 * 8 + r8] + sdv; v3 = (v3 >= 0.f) ? v3 : 0.2f * v3;
            const float al0 = expf(v0 - mm) * zz;
            const float al1 = expf(v1 - mm) * zz;
            const float al2 = expf(v2 - mm) * zz;
            const float al3 = expf(v3 - mm) * zz;
            const ushort4 h0 = *(const ushort4*)&h_ab[(size_t)s0 * HD2 + hoff + c4];
            const ushort4 h1 = *(const ushort4*)&h_ab[(size_t)s1 * HD2 + hoff + c4];
            const ushort4 h2 = *(const ushort4*)&h_ab[(size_t)s2 * HD2 + hoff + c4];
            const ushort4 h3 = *(const ushort4*)&h_ab[(size_t)s3 * HD2 + hoff + c4];
            a.x = fmaf(al0, bf2f(h0.x), a.x); a.y = fmaf(al0, bf2f(h0.y), a.y);
            a.z = fmaf(al0, bf2f(h0.z), a.z); a.w = fmaf(al0, bf2f(h0.w), a.w);
            a.x = fmaf(al1, bf2f(h1.x), a.x); a.y = fmaf(al1, bf2f(h1.y), a.y);
            a.z = fmaf(al1, bf2f(h1.z), a.z); a.w = fmaf(al1, bf2f(h1.w), a.w);
            a.x = fmaf(al2, bf2f(h2.x), a.x); a.y = fmaf(al2, bf2f(h2.y), a.y);
            a.z = fmaf(al2, bf2f(h2.z), a.z); a.w = fmaf(al2, bf2f(h2.w), a.w);
            a.x = fmaf(al3, bf2f(h3.x), a.x); a.y = fmaf(al3, bf2f(h3.y), a.y);
            a.z = fmaf(al3, bf2f(h3.z), a.z); a.w = fmaf(al3, bf2f(h3.w), a.w);
        }
        for (; e < end; e++) {
            const int src = cs[e];
            float v0 = ssrc8[src * 8 + r8] + sdv; v0 = (v0 >= 0.f) ? v0 : 0.2f * v0;
            const float al = expf(v0 - mm) * zz;
            const ushort4 hv = *(const ushort4*)&h_ab[(size_t)src * HD2 + hoff + c4];
            a.x = fmaf(al, bf2f(hv.x), a.x);
            a.y = fmaf(al, bf2f(hv.y), a.y);
            a.z = fmaf(al, bf2f(hv.z), a.z);
            a.w = fmaf(al, bf2f(hv.w), a.w);
        }
    }

    const float4 bv1 = *(const float4*)&b1[c4];
    const float4 bv2 = *(const float4*)&b2[c4];
    float4 v;
    v.x = a.x + bv1.x + bv2.x;
    v.y = a.y + bv1.y + bv2.y;
    v.z = a.z + bv1.z + bv2.z;
    v.w = a.w + bv1.w + bv2.w;
    if (do_leaky) {
        v.x = (v.x >= 0.f) ? v.x : 0.01f * v.x;
        v.y = (v.y >= 0.f) ? v.y : 0.01f * v.y;
        v.z = (v.z >= 0.f) ? v.z : 0.01f * v.z;
        v.w = (v.w >= 0.f) ? v.w : 0.01f * v.w;
    }
    ushort4 o;
    o.x = f2bf(v.x); o.y = f2bf(v.y); o.z = f2bf(v.z); o.w = f2bf(v.w);
    *(ushort4*)&out_bf[(size_t)node * HD + c4] = o;
}

// ---------- host-side helpers ----------
static void run_layer(const unsigned short* a_bf,
                      const int* rp_a, const int* cs_a,
                      const int* rp_b, const int* cs_b,
                      const float* Wa, const float* Wb,
                      const float* as_a, const float* ad_a,
                      const float* as_b, const float* ad_b,
                      const float* b1, const float* b2,
                      unsigned short* Wt2, unsigned short* h_ab,
                      float* ssrc8, float* sdst8, float* m8, float* zr8,
                      unsigned short* out_bf, int do_leaky,
                      hipStream_t stream) {
    wt2_kernel<<<HD2, 256, 0, stream>>>(Wa, Wb, Wt2);
    dim3 ggrid(HD2 / 64, (N_NODES + 255) / 256);   // col-block FASTEST
    gemm_k256<<<ggrid, 256, 0, stream>>>(a_bf, Wt2, nullptr, h_ab, nullptr,
                                         N_NODES, HD2);
    scores2_kernel<<<(N_NODES + 3) / 4, 256, 0, stream>>>(
        h_ab, as_a, ad_a, as_b, ad_b, ssrc8, sdst8);
    seg_mz8_kernel<<<(N_NODES * 8 + 255) / 256, 256, 0, stream>>>(
        rp_a, cs_a, rp_b, cs_b, ssrc8, sdst8, m8, zr8);
    aggregate_both_kernel<<<(N_NODES + 3) / 4, 256, 0, stream>>>(
        rp_a, cs_a, rp_b, cs_b, h_ab, ssrc8, sdst8, m8, zr8,
        b1, b2, out_bf, do_leaky);
}

static void build_csr(const int* ei, int* deg, int* cursor, int* row_ptr,
                      int* col_src, int* col_dst, int* excl, int* bsums,
                      hipStream_t stream) {
    const int nb  = (N_NODES + 255) / 256;
    const int eb  = (E_EDGES + 255) / 256;
    const int sb  = (N_NODES + 1023) / 1024;
    zero_int_kernel<<<nb, 256, 0, stream>>>(deg, N_NODES);
    hist_kernel<<<eb, 256, 0, stream>>>(ei, deg);
    scan_local_kernel<<<sb, 1024, 0, stream>>>(deg, excl, bsums, N_NODES);
    scan_bsums_kernel<<<1, 64, 0, stream>>>(bsums, row_ptr, sb, N_NODES);
    scan_add_kernel<<<nb, 256, 0, stream>>>(excl, bsums, row_ptr, cursor, N_NODES);
    scatter_kernel<<<eb, 256, 0, stream>>>(ei, cursor, col_src, col_dst);
}

extern "C" void kernel_launch(void* const* d_in, const int* in_sizes, int n_in,
                              void* d_out, int out_size, void* d_ws, size_t ws_size,
                              hipStream_t stream) {
    const float* x    = (const float*)d_in[0];
    const int*   ei_a = (const int*)d_in[1];
    const int*   ei_b = (const int*)d_in[2];
    const float* W0a = (const float*)d_in[3];
    const float* as0a = (const float*)d_in[4];
    const float* ad0a = (const float*)d_in[5];
    const float* b0a = (const float*)d_in[6];
    const float* W0b = (const float*)d_in[7];
    const float* as0b = (const float*)d_in[8];
    const float* ad0b = (const float*)d_in[9];
    const float* b0b = (const float*)d_in[10];
    const float* W1a = (const float*)d_in[11];
    const float* as1a = (const float*)d_in[12];
    const float* ad1a = (const float*)d_in[13];
    const float* b1a = (const float*)d_in[14];
    const float* W1b = (const float*)d_in[15];
    const float* as1b = (const float*)d_in[16];
    const float* ad1b = (const float*)d_in[17];
    const float* b1b = (const float*)d_in[18];
    const float* Wout = (const float*)d_in[19];
    const float* bout = (const float*)d_in[20];
    float* out = (float*)d_out;

    // workspace carve
    unsigned short* h_ab  = (unsigned short*)d_ws;          // N*512 ushort
    unsigned short* bf_in = h_ab + (size_t)N_NODES * HD2;   // N*256 ushort
    unsigned short* Wt2   = bf_in + (size_t)N_NODES * HD;   // 512*256 ushort
    float* ssrc8  = (float*)(Wt2 + (size_t)HD2 * KDIM);     // N*8
    float* sdst8  = ssrc8 + (size_t)N_NODES * 8;            // N*8
    float* m8     = sdst8 + (size_t)N_NODES * 8;            // N*8
    float* zr8    = m8 + (size_t)N_NODES * 8;               // N*8
    int*   ibase  = (int*)(zr8 + (size_t)N_NODES * 8);
    int* deg     = ibase;
    int* cursor  = deg + N_NODES;
    int* rp_a    = cursor + N_NODES;
    int* cs_a    = rp_a + N_NODES + 1;
    int* cd_a    = cs_a + E_EDGES;
    int* rp_b    = cd_a + E_EDGES;
    int* cs_b    = rp_b + N_NODES + 1;
    int* cd_b    = cs_b + E_EDGES;
    int* excl    = cd_b + E_EDGES;
    int* bsums   = excl + N_NODES;

    const size_t NF = (size_t)N_NODES * HD;
    const int nf4_blocks = (int)((NF / 4 + 255) / 256);

    // ---- CSR for both edge types (reused by both layers) ----
    build_csr(ei_a, deg, cursor, rp_a, cs_a, cd_a, excl, bsums, stream);
    build_csr(ei_b, deg, cursor, rp_b, cs_b, cd_b, excl, bsums, stream);

    // ---- layer 0 ----
    convert_bf16_kernel<<<nf4_blocks, 256, 0, stream>>>(x, bf_in, (int)NF);
    run_layer(bf_in, rp_a, cs_a, rp_b, cs_b, W0a, W0b,
              as0a, ad0a, as0b, ad0b, b0a, b0b, Wt2, h_ab,
              ssrc8, sdst8, m8, zr8,
              bf_in, /*leaky=*/1, stream);

    // ---- layer 1 ----
    run_layer(bf_in, rp_a, cs_a, rp_b, cs_b, W1a, W1b,
              as1a, ad1a, as1b, ad1b, b1a, b1b, Wt2, h_ab,
              ssrc8, sdst8, m8, zr8,
              bf_in, /*leaky=*/0, stream);

    // ---- output projection ----
    wt_kernel<<<KDIM, 256, 0, stream>>>(Wout, Wt2, NC);
    dim3 ogrid(3, (N_NODES + 255) / 256);   // 3 x 64 cols covers NC=153
    gemm_k256<<<ogrid, 256, 0, stream>>>(bf_in, Wt2, out, nullptr, bout,
                                         N_NODES, NC);
}

// Round 4
// 503.997 us; speedup vs baseline: 1.2154x; 1.0202x over previous
//
#include <hip/hip_runtime.h>
#include <math.h>

#define N_NODES 50000
#define E_EDGES 250000
#define HD 256          // H * D per edge type
#define NH 4
#define DH 64
#define NC 153
#define KDIM 256        // all GEMMs have K = 256
#define HD2 512         // both edge types concatenated

// ---------- fp32 <-> bf16 ----------
__device__ __forceinline__ unsigned short f2bf(float f) {
    unsigned u = __float_as_uint(f);
    u = u + 0x7FFFu + ((u >> 16) & 1u);
    return (unsigned short)(u >> 16);
}
__device__ __forceinline__ float bf2f(unsigned short b) {
    return __uint_as_float(((unsigned)b) << 16);
}

typedef __attribute__((ext_vector_type(8))) short bf16x8;
typedef __attribute__((ext_vector_type(4))) float f32x4;

// ================= K=256 bf16 MFMA GEMM =================
// C[M,Ncols] = A[M,256] @ BT[Ncols,256]^T (+bias), BT zero-padded to NCB*64 rows.
// Block: 256 rows x 64 cols; 4 waves stacked in M share one B tile (64x256 bf16,
// 32KB LDS, XOR-swizzled).
// GRID: 1-D, logical id = rb*NCB + cb (col minor). Bijective XCD swizzle (m204)
// maps dispatch id -> logical id so each XCD gets a CONTIGUOUS logical chunk:
// the NCB col-blocks sharing one 128KB A row-panel run back-to-back on the SAME
// XCD => A is HBM-fetched once, then L2-served (round 3 measured the round-robin
// dispatch scattering panel-mates across XCDs: FETCH 100MB = A x4).
// A: ring-4 register prefetch (issue k+3 while computing k, 240cy tolerance ~ L2
// latency). Combined reg use ~180 stays in the 256 VGPR bucket -> occupancy
// unchanged at 8 waves/CU (m69 bucketing; rounds 0/2/3 all measured ~25%).
template<int NCB>
__global__ __launch_bounds__(256) void gemm_k256(
        const unsigned short* __restrict__ A, const unsigned short* __restrict__ BT,
        float* __restrict__ Cf, unsigned short* __restrict__ Cbf,
        const float* __restrict__ bias, int M, int Ncols) {
    __shared__ unsigned short Bs[64 * 256];   // 32 KB, swizzled
    const int tid = threadIdx.x;
    const int lane = tid & 63;
    const int wave = tid >> 6;
    const int quad = lane >> 4;
    const int l16 = lane & 15;

    // ---- bijective XCD swizzle: dispatch wg -> logical ----
    const int nwg = gridDim.x;
    const int wg = blockIdx.x;
    const int x = wg & 7, ii = wg >> 3;
    const int q = nwg >> 3, r = nwg & 7;
    const int logical = (x < r ? x * (q + 1) : r * (q + 1) + (x - r) * q) + ii;
    const int cb = logical % NCB;
    const int rb = logical / NCB;
    const int row0 = rb * 256 + wave * 64;
    const int col0 = cb * 64;

    // ---- stage B(col0..col0+63, 0..255) -> LDS with XOR swizzle ----
    #pragma unroll
    for (int j = 0; j < 8; j++) {
        const int c = tid + 256 * j;         // 16B chunk id (2048 total)
        const int rr = c >> 5;               // B row (0..63), 32 chunks/row
        const int kb = (c & 31) << 4;        // byte offset within 512B row
        const uint4 v = *(const uint4*)((const char*)BT +
                            (size_t)(col0 + rr) * 512 + kb);
        *(uint4*)((char*)Bs + rr * 512 + (kb ^ ((rr & 7) << 4))) = v;
    }
    __syncthreads();

    f32x4 acc[4][4];
    #pragma unroll
    for (int i = 0; i < 4; i++)
        #pragma unroll
        for (int j = 0; j < 4; j++) acc[i][j] = (f32x4)0.f;

    size_t a_off[4];
    #pragma unroll
    for (int mt = 0; mt < 4; mt++) {
        int gr = row0 + mt * 16 + l16;
        if (gr >= M) gr = M - 1;
        a_off[mt] = (size_t)gr * KDIM + quad * 8;
    }
    // B fragment addressing: row = nt*16+l16, byte = (kk*64 + quad*16) ^ ((l16&7)<<4)
    // kk*64 bits disjoint from (quad*16 ^ swz) after folding -> single XOR walks K.
    const char* Bsc = (const char*)Bs;
    const int bbase = l16 * 512 + ((quad * 16) ^ ((l16 & 7) << 4));

    bf16x8 a_buf[4][4];    // [ring slot][mt], ring-4: 3 slots in flight
    bf16x8 b_cur[4], b_nxt[4];
    #pragma unroll
    for (int s = 0; s < 3; s++)
        #pragma unroll
        for (int mt = 0; mt < 4; mt++)
            a_buf[s][mt] = *(const bf16x8*)&A[a_off[mt] + s * 32];
    #pragma unroll
    for (int nt = 0; nt < 4; nt++)
        b_cur[nt] = *(const bf16x8*)(Bsc + nt * 16 * 512 + bbase);

    #pragma unroll
    for (int kk = 0; kk < 8; kk++) {
        if (kk + 3 < 8) {
            #pragma unroll
            for (int mt = 0; mt < 4; mt++)
                a_buf[(kk + 3) & 3][mt] =
                    *(const bf16x8*)&A[a_off[mt] + (kk + 3) * 32];
        }
        if (kk < 7) {
            #pragma unroll
            for (int nt = 0; nt < 4; nt++)
                b_nxt[nt] = *(const bf16x8*)(Bsc + nt * 16 * 512 +
                                (bbase ^ ((kk + 1) * 64)));
        }
        #pragma unroll
        for (int mt = 0; mt < 4; mt++)
            #pragma unroll
            for (int nt = 0; nt < 4; nt++)
                acc[mt][nt] = __builtin_amdgcn_mfma_f32_16x16x32_bf16(
                                  a_buf[kk & 3][mt], b_cur[nt], acc[mt][nt], 0, 0, 0);
        #pragma unroll
        for (int nt = 0; nt < 4; nt++) b_cur[nt] = b_nxt[nt];
    }

    #pragma unroll
    for (int mt = 0; mt < 4; mt++) {
        #pragma unroll
        for (int nt = 0; nt < 4; nt++) {
            const int n = col0 + nt * 16 + l16;
            if (n >= Ncols) continue;
            const float bv = bias ? bias[n] : 0.f;
            #pragma unroll
            for (int rr = 0; rr < 4; rr++) {
                const int m = row0 + mt * 16 + quad * 4 + rr;
                if (m < M) {
                    const float v = acc[mt][nt][rr] + bv;
                    if (Cf)  Cf[(size_t)m * Ncols + n] = v;
                    if (Cbf) Cbf[(size_t)m * Ncols + n] = f2bf(v);
                }
            }
        }
    }
}

// ---------- fp32 -> bf16 conversion (vectorized) ----------
__global__ __launch_bounds__(256) void convert_bf16_kernel(
        const float* __restrict__ in, unsigned short* __restrict__ out, int n) {
    const int i = (blockIdx.x * 256 + threadIdx.x) * 4;
    if (i + 3 < n) {
        const float4 v = *(const float4*)&in[i];
        ushort4 o;
        o.x = f2bf(v.x); o.y = f2bf(v.y); o.z = f2bf(v.z); o.w = f2bf(v.w);
        *(ushort4*)&out[i] = o;
    } else {
        for (int j = i; j < n; j++) out[j] = f2bf(in[j]);
    }
}

// ---------- dual weight transpose+convert: Wa,Wb[K,256] -> Wt[512,K] bf16 ----------
__global__ __launch_bounds__(256) void wt2_kernel(
        const float* __restrict__ Wa, const float* __restrict__ Wb,
        unsigned short* __restrict__ Wt) {
    const int idx = blockIdx.x * 256 + threadIdx.x;
    const int n = idx >> 8, k = idx & 255;
    Wt[idx] = (n < HD) ? f2bf(Wa[(size_t)k * HD + n])
                       : f2bf(Wb[(size_t)k * HD + (n - HD)]);
}

// ---------- single weight transpose+convert with zero-pad to 256 rows ----------
__global__ __launch_bounds__(256) void wt_kernel(
        const float* __restrict__ W, unsigned short* __restrict__ Wt, int Nc) {
    const int idx = blockIdx.x * 256 + threadIdx.x;
    const int n = idx >> 8, k = idx & 255;
    Wt[idx] = (n < Nc) ? f2bf(W[(size_t)k * Nc + n]) : (unsigned short)0;
}

// ---------- CSR construction ----------
__global__ __launch_bounds__(256) void zero_int_kernel(int* __restrict__ p, int n) {
    const int i = blockIdx.x * 256 + threadIdx.x;
    if (i < n) p[i] = 0;
}

__global__ __launch_bounds__(256) void hist_kernel(
        const int* __restrict__ ei, int* __restrict__ deg) {
    const int e = blockIdx.x * 256 + threadIdx.x;
    if (e < E_EDGES) atomicAdd(&deg[ei[E_EDGES + e]], 1);
}

__global__ __launch_bounds__(1024) void scan_local_kernel(
        const int* __restrict__ deg, int* __restrict__ excl,
        int* __restrict__ bsums, int n) {
    __shared__ int wsum[16];
    const int i = blockIdx.x * 1024 + threadIdx.x;
    const int lane = threadIdx.x & 63;
    const int wid = threadIdx.x >> 6;
    const int v = (i < n) ? deg[i] : 0;
    int s = v;
    #pragma unroll
    for (int off = 1; off < 64; off <<= 1) {
        const int t = __shfl_up(s, off);
        if (lane >= off) s += t;
    }
    if (lane == 63) wsum[wid] = s;
    __syncthreads();
    if (wid == 0) {
        int wv = (lane < 16) ? wsum[lane] : 0;
        #pragma unroll
        for (int off = 1; off < 16; off <<= 1) {
            const int t = __shfl_up(wv, off);
            if (lane >= off) wv += t;
        }
        if (lane < 16) wsum[lane] = wv;
    }
    __syncthreads();
    const int woff = (wid > 0) ? wsum[wid - 1] : 0;
    if (i < n) excl[i] = s - v + woff;
    if (threadIdx.x == 1023) bsums[blockIdx.x] = wsum[15];
}

__global__ __launch_bounds__(64) void scan_bsums_kernel(
        int* __restrict__ bsums, int* __restrict__ row_ptr, int nb, int n) {
    const int lane = threadIdx.x;
    const int v = (lane < nb) ? bsums[lane] : 0;
    int s = v;
    #pragma unroll
    for (int off = 1; off < 64; off <<= 1) {
        const int t = __shfl_up(s, off);
        if (lane >= off) s += t;
    }
    if (lane < nb) bsums[lane] = s - v;
    if (lane == 63) row_ptr[n] = s;
}

__global__ __launch_bounds__(256) void scan_add_kernel(
        const int* __restrict__ excl, const int* __restrict__ bsums,
        int* __restrict__ row_ptr, int* __restrict__ cursor, int n) {
    const int i = blockIdx.x * 256 + threadIdx.x;
    if (i >= n) return;
    const int v = excl[i] + bsums[i >> 10];
    row_ptr[i] = v;
    cursor[i]  = v;
}

__global__ __launch_bounds__(256) void scatter_kernel(
        const int* __restrict__ ei, int* __restrict__ cursor,
        int* __restrict__ col_src, int* __restrict__ col_dst) {
    const int e = blockIdx.x * 256 + threadIdx.x;
    if (e >= E_EDGES) return;
    const int src = ei[e], dst = ei[E_EDGES + e];
    const int pos = atomicAdd(&cursor[dst], 1);
    col_src[pos] = src;
    col_dst[pos] = dst;
}

// ---------- per-node attention scores for BOTH etypes ----------
__global__ __launch_bounds__(256) void scores2_kernel(
        const unsigned short* __restrict__ h_ab,
        const float* __restrict__ as_a, const float* __restrict__ ad_a,
        const float* __restrict__ as_b, const float* __restrict__ ad_b,
        float* __restrict__ ssrc8, float* __restrict__ sdst8) {
    const int node = blockIdx.x * 4 + (threadIdx.x >> 6);
    const int lane = threadIdx.x & 63;
    if (node >= N_NODES) return;
    const size_t base = (size_t)node * HD2 + lane * 4;

    const ushort4 ha = *(const ushort4*)&h_ab[base];
    const ushort4 hb = *(const ushort4*)&h_ab[base + HD];
    const float4 asa = *(const float4*)&as_a[lane * 4];
    const float4 ada = *(const float4*)&ad_a[lane * 4];
    const float4 asb = *(const float4*)&as_b[lane * 4];
    const float4 adb = *(const float4*)&ad_b[lane * 4];
    const float a0 = bf2f(ha.x), a1 = bf2f(ha.y), a2 = bf2f(ha.z), a3 = bf2f(ha.w);
    const float b0 = bf2f(hb.x), b1 = bf2f(hb.y), b2 = bf2f(hb.z), b3 = bf2f(hb.w);

    float rsa = a0 * asa.x + a1 * asa.y + a2 * asa.z + a3 * asa.w;
    float rda = a0 * ada.x + a1 * ada.y + a2 * ada.z + a3 * ada.w;
    float rsb = b0 * asb.x + b1 * asb.y + b2 * asb.z + b3 * asb.w;
    float rdb = b0 * adb.x + b1 * adb.y + b2 * adb.z + b3 * adb.w;
    #pragma unroll
    for (int off = 1; off < 16; off <<= 1) {
        rsa += __shfl_xor(rsa, off);
        rda += __shfl_xor(rda, off);
        rsb += __shfl_xor(rsb, off);
        rdb += __shfl_xor(rdb, off);
    }
    if ((lane & 15) == 0) {
        const int hh = lane >> 4;
        ssrc8[node * 8 + 0 + hh] = rsa;
        sdst8[node * 8 + 0 + hh] = rda;
        ssrc8[node * 8 + 4 + hh] = rsb;
        sdst8[node * 8 + 4 + hh] = rdb;
    }
}

// ---------- S1: per (node,etype,head) thread computes m and 1/(z+eps) ----------
__global__ __launch_bounds__(256) void seg_mz8_kernel(
        const int* __restrict__ rp_a, const int* __restrict__ cs_a,
        const int* __restrict__ rp_b, const int* __restrict__ cs_b,
        const float* __restrict__ ssrc8, const float* __restrict__ sdst8,
        float* __restrict__ m8, float* __restrict__ zr8) {
    const int t = blockIdx.x * 256 + threadIdx.x;
    if (t >= N_NODES * 8) return;
    const int node = t >> 3;
    const int r8 = t & 7;
    const int et = r8 >> 2;
    const int* rp = et ? rp_b : rp_a;
    const int* cs = et ? cs_b : cs_a;
    const int beg = rp[node], end = rp[node + 1];
    const float sd = sdst8[t];
    float m = -INFINITY;
    for (int e = beg; e < end; e++) {
        float s = ssrc8[cs[e] * 8 + r8] + sd;
        s = (s >= 0.f) ? s : 0.2f * s;
        m = fmaxf(m, s);
    }
    float z = 0.f;
    for (int e = beg; e < end; e++) {
        float s = ssrc8[cs[e] * 8 + r8] + sd;
        s = (s >= 0.f) ? s : 0.2f * s;
        z += expf(s - m);
    }
    m8[t]  = m;
    zr8[t] = 1.f / (z + 1e-16f);
}

// ---------- S3: aggregation with INLINE alpha + fused epilogue ----------
__global__ __launch_bounds__(256) void aggregate_both_kernel(
        const int* __restrict__ rp_a, const int* __restrict__ cs_a,
        const int* __restrict__ rp_b, const int* __restrict__ cs_b,
        const unsigned short* __restrict__ h_ab,
        const float* __restrict__ ssrc8, const float* __restrict__ sdst8,
        const float* __restrict__ m8, const float* __restrict__ zr8,
        const float* __restrict__ b1, const float* __restrict__ b2,
        unsigned short* __restrict__ out_bf, int do_leaky) {
    const int node = blockIdx.x * 4 + (threadIdx.x >> 6);
    const int lane = threadIdx.x & 63;
    if (node >= N_NODES) return;
    const int hh = lane >> 4;
    const int c4 = lane * 4;

    float4 a = make_float4(0.f, 0.f, 0.f, 0.f);

    #pragma unroll
    for (int et = 0; et < 2; et++) {
        const int* rp = et ? rp_b : rp_a;
        const int* cs = et ? cs_b : cs_a;
        const size_t hoff = et ? (size_t)HD : 0;
        const int r8 = et * 4 + hh;
        const float sdv = sdst8[node * 8 + r8];
        const float mm  = m8[node * 8 + r8];
        const float zz  = zr8[node * 8 + r8];
        const int beg = rp[node], end = rp[node + 1];
        int e = beg;
        for (; e + 3 < end; e += 4) {
            const int s0 = cs[e + 0], s1 = cs[e + 1],
                      s2 = cs[e + 2], s3 = cs[e + 3];
            float v0 = ssrc8[s0 * 8 + r8] + sdv; v0 = (v0 >= 0.f) ? v0 : 0.2f * v0;
            float v1 = ssrc8[s1 * 8 + r8] + sdv; v1 = (v1 >= 0.f) ? v1 : 0.2f * v1;
            float v2 = ssrc8[s2 * 8 + r8] + sdv; v2 = (v2 >= 0.f) ? v2 : 0.2f * v2;
            float v3 = ssrc8[s3 * 8 + r8] + sdv; v3 = (v3 >= 0.f) ? v3 : 0.2f * v3;
            const float al0 = expf(v0 - mm) * zz;
            const float al1 = expf(v1 - mm) * zz;
            const float al2 = expf(v2 - mm) * zz;
            const float al3 = expf(v3 - mm) * zz;
            const ushort4 h0 = *(const ushort4*)&h_ab[(size_t)s0 * HD2 + hoff + c4];
            const ushort4 h1 = *(const ushort4*)&h_ab[(size_t)s1 * HD2 + hoff + c4];
            const ushort4 h2 = *(const ushort4*)&h_ab[(size_t)s2 * HD2 + hoff + c4];
            const ushort4 h3 = *(const ushort4*)&h_ab[(size_t)s3 * HD2 + hoff + c4];
            a.x = fmaf(al0, bf2f(h0.x), a.x); a.y = fmaf(al0, bf2f(h0.y), a.y);
            a.z = fmaf(al0, bf2f(h0.z), a.z); a.w = fmaf(al0, bf2f(h0.w), a.w);
            a.x = fmaf(al1, bf2f(h1.x), a.x); a.y = fmaf(al1, bf2f(h1.y), a.y);
            a.z = fmaf(al1, bf2f(h1.z), a.z); a.w = fmaf(al1, bf2f(h1.w), a.w);
            a.x = fmaf(al2, bf2f(h2.x), a.x); a.y = fmaf(al2, bf2f(h2.y), a.y);
            a.z = fmaf(al2, bf2f(h2.z), a.z); a.w = fmaf(al2, bf2f(h2.w), a.w);
            a.x = fmaf(al3, bf2f(h3.x), a.x); a.y = fmaf(al3, bf2f(h3.y), a.y);
            a.z = fmaf(al3, bf2f(h3.z), a.z); a.w = fmaf(al3, bf2f(h3.w), a.w);
        }
        for (; e < end; e++) {
            const int src = cs[e];
            float v0 = ssrc8[src * 8 + r8] + sdv; v0 = (v0 >= 0.f) ? v0 : 0.2f * v0;
            const float al = expf(v0 - mm) * zz;
            const ushort4 hv = *(const ushort4*)&h_ab[(size_t)src * HD2 + hoff + c4];
            a.x = fmaf(al, bf2f(hv.x), a.x);
            a.y = fmaf(al, bf2f(hv.y), a.y);
            a.z = fmaf(al, bf2f(hv.z), a.z);
            a.w = fmaf(al, bf2f(hv.w), a.w);
        }
    }

    const float4 bv1 = *(const float4*)&b1[c4];
    const float4 bv2 = *(const float4*)&b2[c4];
    float4 v;
    v.x = a.x + bv1.x + bv2.x;
    v.y = a.y + bv1.y + bv2.y;
    v.z = a.z + bv1.z + bv2.z;
    v.w = a.w + bv1.w + bv2.w;
    if (do_leaky) {
        v.x = (v.x >= 0.f) ? v.x : 0.01f * v.x;
        v.y = (v.y >= 0.f) ? v.y : 0.01f * v.y;
        v.z = (v.z >= 0.f) ? v.z : 0.01f * v.z;
        v.w = (v.w >= 0.f) ? v.w : 0.01f * v.w;
    }
    ushort4 o;
    o.x = f2bf(v.x); o.y = f2bf(v.y); o.z = f2bf(v.z); o.w = f2bf(v.w);
    *(ushort4*)&out_bf[(size_t)node * HD + c4] = o;
}

// ---------- host-side helpers ----------
#define N_ROWBLK ((N_NODES + 255) / 256)

static void run_layer(const unsigned short* a_bf,
                      const int* rp_a, const int* cs_a,
                      const int* rp_b, const int* cs_b,
                      const float* Wa, const float* Wb,
                      const float* as_a, const float* ad_a,
                      const float* as_b, const float* ad_b,
                      const float* b1, const float* b2,
                      unsigned short* Wt2, unsigned short* h_ab,
                      float* ssrc8, float* sdst8, float* m8, float* zr8,
                      unsigned short* out_bf, int do_leaky,
                      hipStream_t stream) {
    wt2_kernel<<<HD2, 256, 0, stream>>>(Wa, Wb, Wt2);
    gemm_k256<8><<<N_ROWBLK * 8, 256, 0, stream>>>(
        a_bf, Wt2, nullptr, h_ab, nullptr, N_NODES, HD2);
    scores2_kernel<<<(N_NODES + 3) / 4, 256, 0, stream>>>(
        h_ab, as_a, ad_a, as_b, ad_b, ssrc8, sdst8);
    seg_mz8_kernel<<<(N_NODES * 8 + 255) / 256, 256, 0, stream>>>(
        rp_a, cs_a, rp_b, cs_b, ssrc8, sdst8, m8, zr8);
    aggregate_both_kernel<<<(N_NODES + 3) / 4, 256, 0, stream>>>(
        rp_a, cs_a, rp_b, cs_b, h_ab, ssrc8, sdst8, m8, zr8,
        b1, b2, out_bf, do_leaky);
}

static void build_csr(const int* ei, int* deg, int* cursor, int* row_ptr,
                      int* col_src, int* col_dst, int* excl, int* bsums,
                      hipStream_t stream) {
    const int nb  = (N_NODES + 255) / 256;
    const int eb  = (E_EDGES + 255) / 256;
    const int sb  = (N_NODES + 1023) / 1024;
    zero_int_kernel<<<nb, 256, 0, stream>>>(deg, N_NODES);
    hist_kernel<<<eb, 256, 0, stream>>>(ei, deg);
    scan_local_kernel<<<sb, 1024, 0, stream>>>(deg, excl, bsums, N_NODES);
    scan_bsums_kernel<<<1, 64, 0, stream>>>(bsums, row_ptr, sb, N_NODES);
    scan_add_kernel<<<nb, 256, 0, stream>>>(excl, bsums, row_ptr, cursor, N_NODES);
    scatter_kernel<<<eb, 256, 0, stream>>>(ei, cursor, col_src, col_dst);
}

extern "C" void kernel_launch(void* const* d_in, const int* in_sizes, int n_in,
                              void* d_out, int out_size, void* d_ws, size_t ws_size,
                              hipStream_t stream) {
    const float* x    = (const float*)d_in[0];
    const int*   ei_a = (const int*)d_in[1];
    const int*   ei_b = (const int*)d_in[2];
    const float* W0a = (const float*)d_in[3];
    const float* as0a = (const float*)d_in[4];
    const float* ad0a = (const float*)d_in[5];
    const float* b0a = (const float*)d_in[6];
    const float* W0b = (const float*)d_in[7];
    const float* as0b = (const float*)d_in[8];
    const float* ad0b = (const float*)d_in[9];
    const float* b0b = (const float*)d_in[10];
    const float* W1a = (const float*)d_in[11];
    const float* as1a = (const float*)d_in[12];
    const float* ad1a = (const float*)d_in[13];
    const float* b1a = (const float*)d_in[14];
    const float* W1b = (const float*)d_in[15];
    const float* as1b = (const float*)d_in[16];
    const float* ad1b = (const float*)d_in[17];
    const float* b1b = (const float*)d_in[18];
    const float* Wout = (const float*)d_in[19];
    const float* bout = (const float*)d_in[20];
    float* out = (float*)d_out;

    // workspace carve
    unsigned short* h_ab  = (unsigned short*)d_ws;          // N*512 ushort
    unsigned short* bf_in = h_ab + (size_t)N_NODES * HD2;   // N*256 ushort
    unsigned short* Wt2   = bf_in + (size_t)N_NODES * HD;   // 512*256 ushort
    float* ssrc8  = (float*)(Wt2 + (size_t)HD2 * KDIM);     // N*8
    float* sdst8  = ssrc8 + (size_t)N_NODES * 8;            // N*8
    float* m8     = sdst8 + (size_t)N_NODES * 8;            // N*8
    float* zr8    = m8 + (size_t)N_NODES * 8;               // N*8
    int*   ibase  = (int*)(zr8 + (size_t)N_NODES * 8);
    int* deg     = ibase;
    int* cursor  = deg + N_NODES;
    int* rp_a    = cursor + N_NODES;
    int* cs_a    = rp_a + N_NODES + 1;
    int* cd_a    = cs_a + E_EDGES;
    int* rp_b    = cd_a + E_EDGES;
    int* cs_b    = rp_b + N_NODES + 1;
    int* cd_b    = cs_b + E_EDGES;
    int* excl    = cd_b + E_EDGES;
    int* bsums   = excl + N_NODES;

    const size_t NF = (size_t)N_NODES * HD;
    const int nf4_blocks = (int)((NF / 4 + 255) / 256);

    // ---- CSR for both edge types (reused by both layers) ----
    build_csr(ei_a, deg, cursor, rp_a, cs_a, cd_a, excl, bsums, stream);
    build_csr(ei_b, deg, cursor, rp_b, cs_b, cd_b, excl, bsums, stream);

    // ---- layer 0 ----
    convert_bf16_kernel<<<nf4_blocks, 256, 0, stream>>>(x, bf_in, (int)NF);
    run_layer(bf_in, rp_a, cs_a, rp_b, cs_b, W0a, W0b,
              as0a, ad0a, as0b, ad0b, b0a, b0b, Wt2, h_ab,
              ssrc8, sdst8, m8, zr8,
              bf_in, /*leaky=*/1, stream);

    // ---- layer 1 ----
    run_layer(bf_in, rp_a, cs_a, rp_b, cs_b, W1a, W1b,
              as1a, ad1a, as1b, ad1b, b1a, b1b, Wt2, h_ab,
              ssrc8, sdst8, m8, zr8,
              bf_in, /*leaky=*/0, stream);

    // ---- output projection (3 x 64 padded cols covers NC=153) ----
    wt_kernel<<<KDIM, 256, 0, stream>>>(Wout, Wt2, NC);
    gemm_k256<3><<<N_ROWBLK * 3, 256, 0, stream>>>(
        bf_in, Wt2, out, nullptr, bout, N_NODES, NC);
}

// Round 5
// 435.160 us; speedup vs baseline: 1.4077x; 1.1582x over previous
//
#include <hip/hip_runtime.h>
#include <math.h>

#define N_NODES 50000
#define E_EDGES 250000
#define HD 256          // H * D per edge type
#define NH 4
#define DH 64
#define NC 153
#define KDIM 256        // all GEMMs have K = 256
#define HD2 512         // both edge types concatenated

// ---------- fp32 <-> bf16 ----------
__device__ __forceinline__ unsigned short f2bf(float f) {
    unsigned u = __float_as_uint(f);
    u = u + 0x7FFFu + ((u >> 16) & 1u);
    return (unsigned short)(u >> 16);
}
__device__ __forceinline__ float bf2f(unsigned short b) {
    return __uint_as_float(((unsigned)b) << 16);
}

typedef __attribute__((ext_vector_type(8))) short bf16x8;
typedef __attribute__((ext_vector_type(4))) float f32x4;

// ================= K=256 bf16 MFMA GEMM =================
// C[M,Ncols] = A[M,256] @ BT[Ncols,256]^T, BT zero-padded to NCB*64 rows.
// Block: 256 rows x 64 cols; 4 waves stacked in M share one B tile (64x256 bf16,
// 32KB LDS, XOR-swizzled). Bijective XCD swizzle (confirmed r4: FETCH 100->15.7MB).
// A: ring-4 register prefetch.
// SCORES=true (layer GEMMs): a 64-col block == one (etype,head), so the epilogue
// computes the COMPLETE s_src/s_dst dot for that head from acc (16-lane reduce),
// and writes C as bf16 through an LDS transpose: 64 scalar 2B stores/thread ->
// 8 dwordx4 stores/thread. (r0-r4 invariant ~64us = 25.7M store-instr issue bound.)
// SCORES=false (proj): old scalar fp32 path with bias.
template<int NCB, bool SCORES>
__global__ __launch_bounds__(256) void gemm_k256(
        const unsigned short* __restrict__ A, const unsigned short* __restrict__ BT,
        float* __restrict__ Cf, unsigned short* __restrict__ Cbf,
        const float* __restrict__ bias,
        const float* __restrict__ as_a, const float* __restrict__ ad_a,
        const float* __restrict__ as_b, const float* __restrict__ ad_b,
        float* __restrict__ ssrc8, float* __restrict__ sdst8,
        int M, int Ncols) {
    __shared__ unsigned short Bs[64 * 256];   // 32 KB: B tile, then C-transpose buf
    const int tid = threadIdx.x;
    const int lane = tid & 63;
    const int wave = tid >> 6;
    const int quad = lane >> 4;
    const int l16 = lane & 15;

    // ---- bijective XCD swizzle: dispatch wg -> logical (col-minor) ----
    const int nwg = gridDim.x;
    const int wg = blockIdx.x;
    const int x = wg & 7, ii = wg >> 3;
    const int q = nwg >> 3, r = nwg & 7;
    const int logical = (x < r ? x * (q + 1) : r * (q + 1) + (x - r) * q) + ii;
    const int cb = logical % NCB;
    const int rb = logical / NCB;
    const int row0 = rb * 256 + wave * 64;
    const int col0 = cb * 64;

    // ---- stage B(col0..col0+63, 0..255) -> LDS with XOR swizzle ----
    #pragma unroll
    for (int j = 0; j < 8; j++) {
        const int c = tid + 256 * j;         // 16B chunk id (2048 total)
        const int rr = c >> 5;               // B row (0..63)
        const int kb = (c & 31) << 4;        // byte offset within 512B row
        const uint4 v = *(const uint4*)((const char*)BT +
                            (size_t)(col0 + rr) * 512 + kb);
        *(uint4*)((char*)Bs + rr * 512 + (kb ^ ((rr & 7) << 4))) = v;
    }
    __syncthreads();

    f32x4 acc[4][4];
    #pragma unroll
    for (int i = 0; i < 4; i++)
        #pragma unroll
        for (int j = 0; j < 4; j++) acc[i][j] = (f32x4)0.f;

    size_t a_off[4];
    #pragma unroll
    for (int mt = 0; mt < 4; mt++) {
        int gr = row0 + mt * 16 + l16;
        if (gr >= M) gr = M - 1;
        a_off[mt] = (size_t)gr * KDIM + quad * 8;
    }
    const char* Bsc = (const char*)Bs;
    const int bbase = l16 * 512 + ((quad * 16) ^ ((l16 & 7) << 4));

    bf16x8 a_buf[4][4];    // ring-4 A prefetch
    bf16x8 b_cur[4], b_nxt[4];
    #pragma unroll
    for (int s = 0; s < 3; s++)
        #pragma unroll
        for (int mt = 0; mt < 4; mt++)
            a_buf[s][mt] = *(const bf16x8*)&A[a_off[mt] + s * 32];
    #pragma unroll
    for (int nt = 0; nt < 4; nt++)
        b_cur[nt] = *(const bf16x8*)(Bsc + nt * 16 * 512 + bbase);

    #pragma unroll
    for (int kk = 0; kk < 8; kk++) {
        if (kk + 3 < 8) {
            #pragma unroll
            for (int mt = 0; mt < 4; mt++)
                a_buf[(kk + 3) & 3][mt] =
                    *(const bf16x8*)&A[a_off[mt] + (kk + 3) * 32];
        }
        if (kk < 7) {
            #pragma unroll
            for (int nt = 0; nt < 4; nt++)
                b_nxt[nt] = *(const bf16x8*)(Bsc + nt * 16 * 512 +
                                (bbase ^ ((kk + 1) * 64)));
        }
        #pragma unroll
        for (int mt = 0; mt < 4; mt++)
            #pragma unroll
            for (int nt = 0; nt < 4; nt++)
                acc[mt][nt] = __builtin_amdgcn_mfma_f32_16x16x32_bf16(
                                  a_buf[kk & 3][mt], b_cur[nt], acc[mt][nt], 0, 0, 0);
        #pragma unroll
        for (int nt = 0; nt < 4; nt++) b_cur[nt] = b_nxt[nt];
    }

    if constexpr (SCORES) {
        // ---- fused attention scores: this col-block == (etype cb>>2, head cb&3)
        const float* as_p = (cb < 4) ? as_a : as_b;
        const float* ad_p = (cb < 4) ? ad_a : ad_b;
        const int hd = (cb & 3) * 64;
        float asv[4], adv[4];
        #pragma unroll
        for (int nt = 0; nt < 4; nt++) {
            asv[nt] = as_p[hd + nt * 16 + l16];
            adv[nt] = ad_p[hd + nt * 16 + l16];
        }
        #pragma unroll
        for (int mt = 0; mt < 4; mt++) {
            #pragma unroll
            for (int rr = 0; rr < 4; rr++) {
                float ps = acc[mt][0][rr] * asv[0] + acc[mt][1][rr] * asv[1]
                         + acc[mt][2][rr] * asv[2] + acc[mt][3][rr] * asv[3];
                float pd = acc[mt][0][rr] * adv[0] + acc[mt][1][rr] * adv[1]
                         + acc[mt][2][rr] * adv[2] + acc[mt][3][rr] * adv[3];
                #pragma unroll
                for (int off = 1; off < 16; off <<= 1) {
                    ps += __shfl_xor(ps, off);
                    pd += __shfl_xor(pd, off);
                }
                const int m = row0 + mt * 16 + quad * 4 + rr;
                if (l16 == 0 && m < M) {
                    ssrc8[m * 8 + cb] = ps;
                    sdst8[m * 8 + cb] = pd;
                }
            }
        }

        // ---- C write via LDS transpose: 8 dwordx4 stores/thread ----
        __syncthreads();                      // Bs (B tile) no longer needed
        char* myC = (char*)Bs + wave * 8192;  // 64 rows x 64 cols bf16 = 8KB/wave
        #pragma unroll
        for (int mt = 0; mt < 4; mt++)
            #pragma unroll
            for (int nt = 0; nt < 4; nt++)
                #pragma unroll
                for (int rr = 0; rr < 4; rr++)
                    *(unsigned short*)(myC + (mt * 16 + quad * 4 + rr) * 128 +
                                       (nt * 16 + l16) * 2) = f2bf(acc[mt][nt][rr]);
        #pragma unroll
        for (int it = 0; it < 8; it++) {
            const int chunk = it * 64 + lane;
            const int lr = chunk >> 3;            // local row
            const int cbyte = (chunk & 7) * 16;   // byte offset within 128B row
            const uint4 v = *(const uint4*)(myC + lr * 128 + cbyte);
            const int m = row0 + lr;
            if (m < M)
                *(uint4*)((char*)Cbf + ((size_t)m * Ncols + col0) * 2 + cbyte) = v;
        }
    } else {
        #pragma unroll
        for (int mt = 0; mt < 4; mt++) {
            #pragma unroll
            for (int nt = 0; nt < 4; nt++) {
                const int n = col0 + nt * 16 + l16;
                if (n >= Ncols) continue;
                const float bv = bias ? bias[n] : 0.f;
                #pragma unroll
                for (int rr = 0; rr < 4; rr++) {
                    const int m = row0 + mt * 16 + quad * 4 + rr;
                    if (m < M) Cf[(size_t)m * Ncols + n] = acc[mt][nt][rr] + bv;
                }
            }
        }
    }
}

// ---------- fp32 -> bf16 conversion (vectorized) ----------
__global__ __launch_bounds__(256) void convert_bf16_kernel(
        const float* __restrict__ in, unsigned short* __restrict__ out, int n) {
    const int i = (blockIdx.x * 256 + threadIdx.x) * 4;
    if (i + 3 < n) {
        const float4 v = *(const float4*)&in[i];
        ushort4 o;
        o.x = f2bf(v.x); o.y = f2bf(v.y); o.z = f2bf(v.z); o.w = f2bf(v.w);
        *(ushort4*)&out[i] = o;
    } else {
        for (int j = i; j < n; j++) out[j] = f2bf(in[j]);
    }
}

// ---------- dual weight transpose+convert: Wa,Wb[K,256] -> Wt[512,K] bf16 ----------
__global__ __launch_bounds__(256) void wt2_kernel(
        const float* __restrict__ Wa, const float* __restrict__ Wb,
        unsigned short* __restrict__ Wt) {
    const int idx = blockIdx.x * 256 + threadIdx.x;
    const int n = idx >> 8, k = idx & 255;
    Wt[idx] = (n < HD) ? f2bf(Wa[(size_t)k * HD + n])
                       : f2bf(Wb[(size_t)k * HD + (n - HD)]);
}

// ---------- single weight transpose+convert with zero-pad ----------
__global__ __launch_bounds__(256) void wt_kernel(
        const float* __restrict__ W, unsigned short* __restrict__ Wt, int Nc) {
    const int idx = blockIdx.x * 256 + threadIdx.x;
    const int n = idx >> 8, k = idx & 255;
    Wt[idx] = (n < Nc) ? f2bf(W[(size_t)k * Nc + n]) : (unsigned short)0;
}

// ---------- CSR construction, BOTH etypes in one pass (concatenated) ----------
__global__ __launch_bounds__(256) void zero_int_kernel(int* __restrict__ p, int n) {
    const int i = blockIdx.x * 256 + threadIdx.x;
    if (i < n) p[i] = 0;
}

__global__ __launch_bounds__(256) void hist2_kernel(
        const int* __restrict__ ei_a, const int* __restrict__ ei_b,
        int* __restrict__ deg) {
    const int t = blockIdx.x * 256 + threadIdx.x;
    if (t < E_EDGES)          atomicAdd(&deg[ei_a[E_EDGES + t]], 1);
    else if (t < 2 * E_EDGES) atomicAdd(&deg[N_NODES + ei_b[t]], 1);
}

__global__ __launch_bounds__(1024) void scan_local_kernel(
        const int* __restrict__ deg, int* __restrict__ excl,
        int* __restrict__ bsums, int n) {
    __shared__ int wsum[16];
    const int i = blockIdx.x * 1024 + threadIdx.x;
    const int lane = threadIdx.x & 63;
    const int wid = threadIdx.x >> 6;
    const int v = (i < n) ? deg[i] : 0;
    int s = v;
    #pragma unroll
    for (int off = 1; off < 64; off <<= 1) {
        const int t = __shfl_up(s, off);
        if (lane >= off) s += t;
    }
    if (lane == 63) wsum[wid] = s;
    __syncthreads();
    if (wid == 0) {
        int wv = (lane < 16) ? wsum[lane] : 0;
        #pragma unroll
        for (int off = 1; off < 16; off <<= 1) {
            const int t = __shfl_up(wv, off);
            if (lane >= off) wv += t;
        }
        if (lane < 16) wsum[lane] = wv;
    }
    __syncthreads();
    const int woff = (wid > 0) ? wsum[wid - 1] : 0;
    if (i < n) excl[i] = s - v + woff;
    if (threadIdx.x == 1023) bsums[blockIdx.x] = wsum[15];
}

// nb up to 128 (2N/1024 = 98): 2 values per lane
__global__ __launch_bounds__(64) void scan_bsums_kernel(
        int* __restrict__ bsums, int nb) {
    const int lane = threadIdx.x;
    const int b0 = (lane < nb) ? bsums[lane] : 0;
    const int b1 = (64 + lane < nb) ? bsums[64 + lane] : 0;
    int s0 = b0, s1 = b1;
    #pragma unroll
    for (int off = 1; off < 64; off <<= 1) {
        const int t0 = __shfl_up(s0, off);
        const int t1 = __shfl_up(s1, off);
        if (lane >= off) { s0 += t0; s1 += t1; }
    }
    const int tot0 = __shfl(s0, 63);
    bsums[lane] = s0 - b0;
    bsums[64 + lane] = tot0 + s1 - b1;
}

__global__ __launch_bounds__(256) void scan_add2_kernel(
        const int* __restrict__ excl, const int* __restrict__ bsums,
        int* __restrict__ rp_a, int* __restrict__ rp_b,
        int* __restrict__ cursor, int n2) {
    const int i = blockIdx.x * 256 + threadIdx.x;
    if (i >= n2) return;
    const int v = excl[i] + bsums[i >> 10];
    if (i < N_NODES) { rp_a[i] = v; cursor[i] = v; }
    else { const int w = v - E_EDGES; rp_b[i - N_NODES] = w; cursor[i] = w; }
    if (i == 0) { rp_a[N_NODES] = E_EDGES; rp_b[N_NODES] = E_EDGES; }
}

__global__ __launch_bounds__(256) void scatter2_kernel(
        const int* __restrict__ ei_a, const int* __restrict__ ei_b,
        int* __restrict__ cursor,
        int* __restrict__ cs_a, int* __restrict__ cs_b) {
    const int t = blockIdx.x * 256 + threadIdx.x;
    if (t < E_EDGES) {
        const int src = ei_a[t], dst = ei_a[E_EDGES + t];
        cs_a[atomicAdd(&cursor[dst], 1)] = src;
    } else if (t < 2 * E_EDGES) {
        const int src = ei_b[t - E_EDGES], dst = ei_b[t];
        cs_b[atomicAdd(&cursor[N_NODES + dst], 1)] = src;
    }
}

// ---------- fused softmax(m,z) + aggregation + epilogue; wave per node ----------
// Pass 1 (per etype): online m,z over edges, 16-lane parallel per head group.
// Pass 2: gather h_ab[src] with inline alpha = exp(leaky(s)-m)*zr.
__global__ __launch_bounds__(256) void aggregate_both_kernel(
        const int* __restrict__ rp_a, const int* __restrict__ cs_a,
        const int* __restrict__ rp_b, const int* __restrict__ cs_b,
        const unsigned short* __restrict__ h_ab,
        const float* __restrict__ ssrc8, const float* __restrict__ sdst8,
        const float* __restrict__ b1, const float* __restrict__ b2,
        unsigned short* __restrict__ out_bf, int do_leaky) {
    const int node = blockIdx.x * 4 + (threadIdx.x >> 6);
    const int lane = threadIdx.x & 63;
    if (node >= N_NODES) return;
    const int hh = lane >> 4;
    const int l16 = lane & 15;
    const int c4 = lane * 4;

    float4 a = make_float4(0.f, 0.f, 0.f, 0.f);

    #pragma unroll
    for (int et = 0; et < 2; et++) {
        const int* rp = et ? rp_b : rp_a;
        const int* cs = et ? cs_b : cs_a;
        const size_t hoff = et ? (size_t)HD : 0;
        const int r8 = et * 4 + hh;
        const float sdv = sdst8[node * 8 + r8];
        const int beg = rp[node], end = rp[node + 1];

        // ---- pass 1: online m, z (16 edges in parallel per head group) ----
        float mm = -INFINITY, z = 0.f;
        for (int c = beg; c < end; c += 16) {
            const int e = c + l16;
            float s = -INFINITY;
            if (e < end) {
                s = ssrc8[cs[e] * 8 + r8] + sdv;
                s = (s >= 0.f) ? s : 0.2f * s;
            }
            float mx = s;
            #pragma unroll
            for (int off = 1; off < 16; off <<= 1)
                mx = fmaxf(mx, __shfl_xor(mx, off));
            const float mn = fmaxf(mm, mx);
            float ee = (e < end) ? expf(s - mn) : 0.f;
            #pragma unroll
            for (int off = 1; off < 16; off <<= 1)
                ee += __shfl_xor(ee, off);
            z = z * expf(mm - mn) + ee;
            mm = mn;
        }
        const float zz = 1.f / (z + 1e-16f);

        // ---- pass 2: gather + weighted sum ----
        int e = beg;
        for (; e + 3 < end; e += 4) {
            const int s0 = cs[e + 0], s1 = cs[e + 1],
                      s2 = cs[e + 2], s3 = cs[e + 3];
            float v0 = ssrc8[s0 * 8 + r8] + sdv; v0 = (v0 >= 0.f) ? v0 : 0.2f * v0;
            float v1 = ssrc8[s1 * 8 + r8] + sdv; v1 = (v1 >= 0.f) ? v1 : 0.2f * v1;
            float v2 = ssrc8[s2 * 8 + r8] + sdv; v2 = (v2 >= 0.f) ? v2 : 0.2f * v2;
            float v3 = ssrc8[s3 * 8 + r8] + sdv; v3 = (v3 >= 0.f) ? v3 : 0.2f * v3;
            const float al0 = expf(v0 - mm) * zz;
            const float al1 = expf(v1 - mm) * zz;
            const float al2 = expf(v2 - mm) * zz;
            const float al3 = expf(v3 - mm) * zz;
            const ushort4 h0 = *(const ushort4*)&h_ab[(size_t)s0 * HD2 + hoff + c4];
            const ushort4 h1 = *(const ushort4*)&h_ab[(size_t)s1 * HD2 + hoff + c4];
            const ushort4 h2 = *(const ushort4*)&h_ab[(size_t)s2 * HD2 + hoff + c4];
            const ushort4 h3 = *(const ushort4*)&h_ab[(size_t)s3 * HD2 + hoff + c4];
            a.x = fmaf(al0, bf2f(h0.x), a.x); a.y = fmaf(al0, bf2f(h0.y), a.y);
            a.z = fmaf(al0, bf2f(h0.z), a.z); a.w = fmaf(al0, bf2f(h0.w), a.w);
            a.x = fmaf(al1, bf2f(h1.x), a.x); a.y = fmaf(al1, bf2f(h1.y), a.y);
            a.z = fmaf(al1, bf2f(h1.z), a.z); a.w = fmaf(al1, bf2f(h1.w), a.w);
            a.x = fmaf(al2, bf2f(h2.x), a.x); a.y = fmaf(al2, bf2f(h2.y), a.y);
            a.z = fmaf(al2, bf2f(h2.z), a.z); a.w = fmaf(al2, bf2f(h2.w), a.w);
            a.x = fmaf(al3, bf2f(h3.x), a.x); a.y = fmaf(al3, bf2f(h3.y), a.y);
            a.z = fmaf(al3, bf2f(h3.z), a.z); a.w = fmaf(al3, bf2f(h3.w), a.w);
        }
        for (; e < end; e++) {
            const int src = cs[e];
            float v0 = ssrc8[src * 8 + r8] + sdv; v0 = (v0 >= 0.f) ? v0 : 0.2f * v0;
            const float al = expf(v0 - mm) * zz;
            const ushort4 hv = *(const ushort4*)&h_ab[(size_t)src * HD2 + hoff + c4];
            a.x = fmaf(al, bf2f(hv.x), a.x);
            a.y = fmaf(al, bf2f(hv.y), a.y);
            a.z = fmaf(al, bf2f(hv.z), a.z);
            a.w = fmaf(al, bf2f(hv.w), a.w);
        }
    }

    const float4 bv1 = *(const float4*)&b1[c4];
    const float4 bv2 = *(const float4*)&b2[c4];
    float4 v;
    v.x = a.x + bv1.x + bv2.x;
    v.y = a.y + bv1.y + bv2.y;
    v.z = a.z + bv1.z + bv2.z;
    v.w = a.w + bv1.w + bv2.w;
    if (do_leaky) {
        v.x = (v.x >= 0.f) ? v.x : 0.01f * v.x;
        v.y = (v.y >= 0.f) ? v.y : 0.01f * v.y;
        v.z = (v.z >= 0.f) ? v.z : 0.01f * v.z;
        v.w = (v.w >= 0.f) ? v.w : 0.01f * v.w;
    }
    ushort4 o;
    o.x = f2bf(v.x); o.y = f2bf(v.y); o.z = f2bf(v.z); o.w = f2bf(v.w);
    *(ushort4*)&out_bf[(size_t)node * HD + c4] = o;
}

// ---------- host side ----------
#define N_ROWBLK ((N_NODES + 255) / 256)

static void run_layer(const unsigned short* a_bf,
                      const int* rp_a, const int* cs_a,
                      const int* rp_b, const int* cs_b,
                      const float* Wa, const float* Wb,
                      const float* as_a, const float* ad_a,
                      const float* as_b, const float* ad_b,
                      const float* b1, const float* b2,
                      unsigned short* Wt2, unsigned short* h_ab,
                      float* ssrc8, float* sdst8,
                      unsigned short* out_bf, int do_leaky,
                      hipStream_t stream) {
    wt2_kernel<<<HD2, 256, 0, stream>>>(Wa, Wb, Wt2);
    gemm_k256<8, true><<<N_ROWBLK * 8, 256, 0, stream>>>(
        a_bf, Wt2, nullptr, h_ab, nullptr,
        as_a, ad_a, as_b, ad_b, ssrc8, sdst8, N_NODES, HD2);
    aggregate_both_kernel<<<(N_NODES + 3) / 4, 256, 0, stream>>>(
        rp_a, cs_a, rp_b, cs_b, h_ab, ssrc8, sdst8,
        b1, b2, out_bf, do_leaky);
}

extern "C" void kernel_launch(void* const* d_in, const int* in_sizes, int n_in,
                              void* d_out, int out_size, void* d_ws, size_t ws_size,
                              hipStream_t stream) {
    const float* x    = (const float*)d_in[0];
    const int*   ei_a = (const int*)d_in[1];
    const int*   ei_b = (const int*)d_in[2];
    const float* W0a = (const float*)d_in[3];
    const float* as0a = (const float*)d_in[4];
    const float* ad0a = (const float*)d_in[5];
    const float* b0a = (const float*)d_in[6];
    const float* W0b = (const float*)d_in[7];
    const float* as0b = (const float*)d_in[8];
    const float* ad0b = (const float*)d_in[9];
    const float* b0b = (const float*)d_in[10];
    const float* W1a = (const float*)d_in[11];
    const float* as1a = (const float*)d_in[12];
    const float* ad1a = (const float*)d_in[13];
    const float* b1a = (const float*)d_in[14];
    const float* W1b = (const float*)d_in[15];
    const float* as1b = (const float*)d_in[16];
    const float* ad1b = (const float*)d_in[17];
    const float* b1b = (const float*)d_in[18];
    const float* Wout = (const float*)d_in[19];
    const float* bout = (const float*)d_in[20];
    float* out = (float*)d_out;

    // workspace carve
    unsigned short* h_ab  = (unsigned short*)d_ws;          // N*512 ushort
    unsigned short* bf_in = h_ab + (size_t)N_NODES * HD2;   // N*256 ushort
    unsigned short* Wt2   = bf_in + (size_t)N_NODES * HD;   // 512*256 ushort
    float* ssrc8  = (float*)(Wt2 + (size_t)HD2 * KDIM);     // N*8
    float* sdst8  = ssrc8 + (size_t)N_NODES * 8;            // N*8
    int*   ibase  = (int*)(sdst8 + (size_t)N_NODES * 8);
    int* deg     = ibase;                  // 2N (concat a|b)
    int* cursor  = deg + 2 * N_NODES;      // 2N
    int* rp_a    = cursor + 2 * N_NODES;   // N+1
    int* cs_a    = rp_a + N_NODES + 1;     // E
    int* rp_b    = cs_a + E_EDGES;         // N+1
    int* cs_b    = rp_b + N_NODES + 1;     // E
    int* excl    = cs_b + E_EDGES;         // 2N
    int* bsums   = excl + 2 * N_NODES;     // 128

    const size_t NF = (size_t)N_NODES * HD;
    const int nf4_blocks = (int)((NF / 4 + 255) / 256);
    const int n2 = 2 * N_NODES;
    const int sb = (n2 + 1023) / 1024;     // 98

    // ---- CSR for both edge types in one fused pipeline ----
    zero_int_kernel<<<(n2 + 255) / 256, 256, 0, stream>>>(deg, n2);
    hist2_kernel<<<(2 * E_EDGES + 255) / 256, 256, 0, stream>>>(ei_a, ei_b, deg);
    scan_local_kernel<<<sb, 1024, 0, stream>>>(deg, excl, bsums, n2);
    scan_bsums_kernel<<<1, 64, 0, stream>>>(bsums, sb);
    scan_add2_kernel<<<(n2 + 255) / 256, 256, 0, stream>>>(
        excl, bsums, rp_a, rp_b, cursor, n2);
    scatter2_kernel<<<(2 * E_EDGES + 255) / 256, 256, 0, stream>>>(
        ei_a, ei_b, cursor, cs_a, cs_b);

    // ---- layer 0 ----
    convert_bf16_kernel<<<nf4_blocks, 256, 0, stream>>>(x, bf_in, (int)NF);
    run_layer(bf_in, rp_a, cs_a, rp_b, cs_b, W0a, W0b,
              as0a, ad0a, as0b, ad0b, b0a, b0b, Wt2, h_ab,
              ssrc8, sdst8, bf_in, /*leaky=*/1, stream);

    // ---- layer 1 ----
    run_layer(bf_in, rp_a, cs_a, rp_b, cs_b, W1a, W1b,
              as1a, ad1a, as1b, ad1b, b1a, b1b, Wt2, h_ab,
              ssrc8, sdst8, bf_in, /*leaky=*/0, stream);

    // ---- output projection (3 x 64 padded cols covers NC=153) ----
    wt_kernel<<<KDIM, 256, 0, stream>>>(Wout, Wt2, NC);
    gemm_k256<3, false><<<N_ROWBLK * 3, 256, 0, stream>>>(
        bf_in, Wt2, out, nullptr, bout,
        nullptr, nullptr, nullptr, nullptr, nullptr, nullptr, N_NODES, NC);
}